// Round 6
// baseline (783.026 us; speedup 1.0000x reference)
//
#include <hip/hip_runtime.h>
#include <hip/hip_fp16.h>

// Weight-stationary LSTM classifier, h-only exchange + barrier-overlapped
// x-GEMM. B=4096(+64 pad), T=22, E=H=300.
// Grid 248 = 8 XCDs x 31 slots; L=(b&7)*31+b/8 (XCD-chunked L2 locality).
// L<247: mb=L/19 (320 rows), nb=L%19 (16 jh x 4 gates). W block (64 cols x
// [x:320|h:320] k fp16 = 83KB) LDS-stationary. Per step:
//   xpart(t):  acc = bias + x_t @ Wih   (embed read f32->cvt, NO exchange)
//   [wait barrier t] hpart(t): acc += h_t @ Whh (h from global dbuf)
//   gates in-register; h_{t+1} stored fp16 to other buffer
//   arrive(); xpart(t+1) OVERLAPS barrier latency; wait()
// Hierarchical barrier (8 XCD lines + global line), acq/rel only where needed.
// d_ws: [0,8KB) barrier lines, then 2 x 4160x320 fp16 h-buffers (5.3 MB).

#define TT 22
#define STEPS 22
#define NB 19
#define MBC 13
#define NACT (NB * MBC)          // 247 active
#define NWG 248                  // 8 x 31 (1 dummy, barrier-only)
#define HSTR 320                 // exchange row stride (halves): 300 h + pad
#define WLS 648                  // LDS W col stride (halves), 640 + 8 pad
#define BUFROWS 4160
#define BUFELT ((size_t)BUFROWS * HSTR)

typedef _Float16 f16;
typedef _Float16 f16x8 __attribute__((ext_vector_type(8)));
typedef float    f32x4 __attribute__((ext_vector_type(4)));

__device__ __forceinline__ float sigm(float x) { return 1.0f / (1.0f + __expf(-x)); }
__device__ __forceinline__ float tanh_f(float x) {
    float ax = fabsf(x);
    float e = __expf(-2.0f * ax);
    return copysignf((1.0f - e) / (1.0f + e), x);
}
__device__ __forceinline__ f16x8 pack8(float4 a, float4 b) {
    f16x8 v;
    v[0] = (f16)a.x; v[1] = (f16)a.y; v[2] = (f16)a.z; v[3] = (f16)a.w;
    v[4] = (f16)b.x; v[5] = (f16)b.y; v[6] = (f16)b.z; v[7] = (f16)b.w;
    return v;
}

__global__ __launch_bounds__(256, 1)
void lstm_ws(const int* __restrict__ cap, const int* __restrict__ cap_len,
             const float* __restrict__ embed,
             const float* __restrict__ Wih, const float* __restrict__ Whh,
             const float* __restrict__ bih, const float* __restrict__ bhh,
             const float* __restrict__ v_wn, const float* __restrict__ g_wn,
             const float* __restrict__ b_cls,
             f16* __restrict__ buf0, f16* __restrict__ buf1,
             unsigned* __restrict__ bar, float* __restrict__ out)
{
    __shared__ f16 Wl[64 * WLS];     // 83 KB stationary weights (x|h halves)
    __shared__ int capS[320][TT];    // 28 KB: all tokens of this mb block
    __shared__ float scaleS[2];

    const int tid = threadIdx.x;
    const int b   = blockIdx.x;
    const int grp = b & 7;                     // 8 groups x exactly 31
    const int L   = grp * 31 + (b >> 3);       // XCD-chunked logical id

    unsigned* locCnt  = bar + grp * 64;        // 256B-separated lines
    unsigned* locRel  = bar + 512 + grp * 64;
    unsigned* glob    = bar + 1024;
    unsigned* globRel = bar + 1088;

    unsigned bk = 0;
    bool lead = false;
    auto arrive = [&]() {
        ++bk;
        __syncthreads();   // drains all waves' vmem (stores visible in L2)
        if (tid == 0) {
            unsigned old = __hip_atomic_fetch_add(locCnt, 1u, __ATOMIC_ACQ_REL,
                                                  __HIP_MEMORY_SCOPE_AGENT);
            if (old == bk * 31u - 1u) {        // last in group
                lead = true;
                unsigned go = __hip_atomic_fetch_add(glob, 1u, __ATOMIC_ACQ_REL,
                                                     __HIP_MEMORY_SCOPE_AGENT);
                if (go == bk * 8u - 1u)        // last group: release all
                    __hip_atomic_store(globRel, bk, __ATOMIC_RELEASE,
                                       __HIP_MEMORY_SCOPE_AGENT);
            } else {
                lead = false;
            }
        }
    };
    auto wait = [&]() {
        if (tid == 0) {
            if (lead) {
                while (__hip_atomic_load(globRel, __ATOMIC_RELAXED,
                                         __HIP_MEMORY_SCOPE_AGENT) < bk)
                    __builtin_amdgcn_s_sleep(1);
                (void)__hip_atomic_load(globRel, __ATOMIC_ACQUIRE,
                                        __HIP_MEMORY_SCOPE_AGENT);
                __hip_atomic_store(locRel, bk, __ATOMIC_RELEASE,
                                   __HIP_MEMORY_SCOPE_AGENT);
            } else {
                while (__hip_atomic_load(locRel, __ATOMIC_RELAXED,
                                         __HIP_MEMORY_SCOPE_AGENT) < bk)
                    __builtin_amdgcn_s_sleep(1);
                (void)__hip_atomic_load(locRel, __ATOMIC_ACQUIRE,
                                        __HIP_MEMORY_SCOPE_AGENT);
            }
        }
        __syncthreads();
    };

    if (L >= NACT) {                  // dummy wg: barriers only
        for (int i = 0; i < STEPS; ++i) { arrive(); wait(); }
        return;
    }

    const int mb = L / NB;
    const int nb = L - mb * NB;
    const int mrow0 = mb * 320;
    const int wv = tid >> 6, ln = tid & 63, c = ln & 15, kg = ln >> 4;

    // ---- W block -> LDS: col=g*16+cc, k-layout [0,300)=Wih, [320,620)=Whh ----
    for (int u = tid; u < 64 * 80; u += 256) {
        int col = u / 80, k8 = u - col * 80;
        int g = col >> 4, cc = col & 15;
        int jh0 = nb * 16 + cc;
        int j = g * 300 + jh0;
        f16x8 v;
        #pragma unroll
        for (int i = 0; i < 8; ++i) {
            int kk = k8 * 8 + i;
            float x = 0.f;
            if (jh0 < 300) {
                if (kk < 300)                   x = Wih[(size_t)j * 300 + kk];
                else if (kk >= 320 && kk < 620) x = Whh[(size_t)j * 300 + (kk - 320)];
            }
            v[i] = (f16)x;
        }
        *(f16x8*)&Wl[col * WLS + k8 * 8] = v;
    }

    // all 320 rows' tokens for this mb block
    for (int u = tid; u < 320 * TT; u += 256) {
        int r = u / TT, t = u - r * TT;
        int grow = mrow0 + r;
        capS[r][t] = (grow < 4096) ? cap[(size_t)grow * TT + t] : 0;
    }
    if (tid < 2) {
        float s = 0.f;
        for (int k = 0; k < 300; ++k) { float v = v_wn[tid * 300 + k]; s += v * v; }
        scaleS[tid] = g_wn[tid] * rsqrtf(s);
    }
    __syncthreads();

    // per-lane constants
    int aoff[5];
    #pragma unroll
    for (int m = 0; m < 5; ++m)
        aoff[m] = (mrow0 + (wv * 5 + m) * 16 + c) * HSTR + kg * 8;
    int bbx[4], bbh[4];
    #pragma unroll
    for (int g = 0; g < 4; ++g) {
        bbx[g] = (g * 16 + c) * WLS + kg * 8;
        bbh[g] = bbx[g] + 320;
    }
    const int jh = nb * 16 + c;
    float bias[4];
    #pragma unroll
    for (int g = 0; g < 4; ++g) {
        float bv = 0.f;
        if (jh < 300) { int j = g * 300 + jh; bv = bih[j] + bhh[j]; }
        bias[g] = bv;
    }
    int lenr[5][4];
    #pragma unroll
    for (int m = 0; m < 5; ++m) {
        int rb = mrow0 + (wv * 5 + m) * 16 + kg * 4;
        #pragma unroll
        for (int rg = 0; rg < 4; ++rg) {
            int row = rb + rg;
            lenr[m][rg] = (row < 4096) ? cap_len[row] : 0;
        }
    }

    float cst[5][4] = {};
    float hreg[5][4] = {};
    f32x4 acc[5][4];

    auto initacc = [&]() {
        #pragma unroll
        for (int m = 0; m < 5; ++m)
            #pragma unroll
            for (int g = 0; g < 4; ++g) {
                float bv = bias[g];
                f32x4 b4 = {bv, bv, bv, bv};
                acc[m][g] = b4;
            }
    };

    // x-part: acc += x_t @ Wih, reading embed f32 directly (no exchange)
    auto xpart = [&](int t) {
        const float* ep[5];
        #pragma unroll
        for (int m = 0; m < 5; ++m) {
            int rl = (wv * 5 + m) * 16 + c;
            ep[m] = embed + (size_t)capS[rl][t] * 300;
        }
        #pragma unroll
        for (int kt = 0; kt < 9; ++kt) {
            f16x8 av[5];
            #pragma unroll
            for (int m = 0; m < 5; ++m) {
                const float* p = ep[m] + kt * 32 + kg * 8;
                av[m] = pack8(*(const float4*)p, *(const float4*)(p + 4));
            }
            #pragma unroll
            for (int g = 0; g < 4; ++g) {
                f16x8 bv = *(const f16x8*)&Wl[bbx[g] + kt * 32];
                #pragma unroll
                for (int m = 0; m < 5; ++m)
                    acc[m][g] = __builtin_amdgcn_mfma_f32_16x16x32_f16(av[m], bv, acc[m][g], 0, 0, 0);
            }
        }
        // tail chunk kt=9: k 288..319, valid floats 288..299
        {
            f16x8 av[5];
            #pragma unroll
            for (int m = 0; m < 5; ++m) {
                f16x8 v = {0, 0, 0, 0, 0, 0, 0, 0};
                if (kg == 0) {
                    const float* p = ep[m] + 288;
                    v = pack8(*(const float4*)p, *(const float4*)(p + 4));
                } else if (kg == 1) {
                    float4 u = *(const float4*)(ep[m] + 296);
                    v[0] = (f16)u.x; v[1] = (f16)u.y; v[2] = (f16)u.z; v[3] = (f16)u.w;
                }
                av[m] = v;
            }
            #pragma unroll
            for (int g = 0; g < 4; ++g) {
                f16x8 bv = *(const f16x8*)&Wl[bbx[g] + 288];
                #pragma unroll
                for (int m = 0; m < 5; ++m)
                    acc[m][g] = __builtin_amdgcn_mfma_f32_16x16x32_f16(av[m], bv, acc[m][g], 0, 0, 0);
            }
        }
    };

    // h-part: acc += h_t @ Whh, from exchange buffer (zero-padded to 320)
    auto hpart = [&](const f16* bufc) {
        #pragma unroll
        for (int kt = 0; kt < 10; ++kt) {
            f16x8 av[5];
            #pragma unroll
            for (int m = 0; m < 5; ++m)
                av[m] = *(const f16x8*)(bufc + aoff[m] + kt * 32);
            #pragma unroll
            for (int g = 0; g < 4; ++g) {
                f16x8 bv = *(const f16x8*)&Wl[bbh[g] + kt * 32];
                #pragma unroll
                for (int m = 0; m < 5; ++m)
                    acc[m][g] = __builtin_amdgcn_mfma_f32_16x16x32_f16(av[m], bv, acc[m][g], 0, 0, 0);
            }
        }
    };

    initacc();
    xpart(0);          // h_0 = 0: step 0 needs no h-part, no barrier

    #pragma unroll 1
    for (int t = 0; t < STEPS; ++t) {
        if (t > 0) hpart((t & 1) ? buf1 : buf0);
        f16* bufn = (t & 1) ? buf0 : buf1;

        // gate nonlinearities + state update (i/f/g/o same-lane acc regs)
        #pragma unroll
        for (int m = 0; m < 5; ++m) {
            #pragma unroll
            for (int rg = 0; rg < 4; ++rg) {
                bool upd = (t < lenr[m][rg]);
                float iv = sigm(acc[m][0][rg]);
                float fv = sigm(acc[m][1][rg]);
                float gv = tanh_f(acc[m][2][rg]);
                float ov = sigm(acc[m][3][rg]);
                float cn = fv * cst[m][rg] + iv * gv;
                cn = upd ? cn : cst[m][rg];
                cst[m][rg] = cn;
                float hn = ov * tanh_f(cn);
                hreg[m][rg] = upd ? hn : hreg[m][rg];
            }
            if (jh < 300) {
                int rb = mrow0 + (wv * 5 + m) * 16 + kg * 4;
                #pragma unroll
                for (int rg = 0; rg < 4; ++rg)
                    bufn[(size_t)(rb + rg) * HSTR + jh] = (f16)hreg[m][rg];
            }
        }

        arrive();                          // release h_{t+1}
        if (t + 1 < STEPS) {               // overlap barrier with next x-GEMM
            initacc();
            xpart(t + 1);
        }
        wait();                            // acquire all wgs' h_{t+1}
    }

    // ---- head: rows [L*17, L*17+17), 2 classes, 4 k-segments ----
    const f16* hb = buf0;   // final h lives in buf[22&1] = buf0
    for (int u = tid; u < 136; u += 256) {
        int rl = u >> 3, cls = (u >> 2) & 1, seg = u & 3;
        int grow = L * 17 + rl;
        if (grow >= 4096) continue;
        float sc = scaleS[cls];
        const float* vr = v_wn + cls * 300 + seg * 75;
        const f16* hr = hb + (size_t)grow * HSTR + seg * 75;
        float s = 0.f;
        #pragma unroll 5
        for (int k = 0; k < 75; ++k) s += vr[k] * (float)hr[k];
        float part = sc * s + (seg == 0 ? b_cls[cls] : 0.f);
        atomicAdd(out + (size_t)grow * 2 + cls, part);
    }
}

extern "C" void kernel_launch(void* const* d_in, const int* in_sizes, int n_in,
                              void* d_out, int out_size, void* d_ws, size_t ws_size,
                              hipStream_t stream) {
    const int*   cap     = (const int*)  d_in[0];
    const int*   cap_len = (const int*)  d_in[1];
    const float* embed   = (const float*)d_in[2];
    const float* W_ih    = (const float*)d_in[3];
    const float* W_hh    = (const float*)d_in[4];
    const float* b_ih    = (const float*)d_in[5];
    const float* b_hh    = (const float*)d_in[6];
    const float* v_wn    = (const float*)d_in[7];
    const float* g_wn    = (const float*)d_in[8];
    const float* b_cls   = (const float*)d_in[9];
    float* out = (float*)d_out;

    unsigned* bar = (unsigned*)d_ws;
    f16* b0 = (f16*)((char*)d_ws + 8192);
    f16* b1 = b0 + BUFELT;

    size_t need = 8192 + 2 * BUFELT * sizeof(f16);
    hipMemsetAsync(d_ws, 0, need, stream);                  // bufs + barrier lines
    hipMemsetAsync(d_out, 0, (size_t)out_size * 4, stream); // head uses atomicAdd

    lstm_ws<<<NWG, 256, 0, stream>>>(cap, cap_len, embed, W_ih, W_hh, b_ih, b_hh,
                                     v_wn, g_wn, b_cls, b0, b1, bar, out);
}

// Round 7
// 543.472 us; speedup vs baseline: 1.4408x; 1.4408x over previous
//
#include <hip/hip_runtime.h>
#include <hip/hip_fp16.h>

// Weight-stationary LSTM classifier with INDEPENDENT 19-wg groups.
// B=4096(+64 pad), T=22, E=H=300. 13 groups (mb: 320 rows) x 19 wgs
// (nb: 16 jh x 4 gates). W block (64 cols x 608 k fp16 = 79KB) LDS-stationary.
// Sync is per-group only: RMW-free store-release flags (one 128B line per wg),
// lanes 0..18 poll the 19 flags in parallel (relaxed). Exchange buffers are
// per-step VIRGIN slots (rotation depth D from ws_size, ideal 23) so no
// buffer_inv is needed in the loop (one entry acquire-inv for replay hygiene);
// if D<23, slots reused after D steps trigger an acquire-inv on that step.
// Per step: fused K=608 GEMM (A=[x|h] from slot t%D, W from LDS), in-register
// i/f/g/o combine, h fp16 + staged x fp16 into slot (t+1)%D, release flag.
// d_ws: [0,64KB) flags, then D x 4160x608 fp16 slots.

#define TT 22
#define STEPS 22
#define NB 19
#define MBC 13
#define NACT (NB * MBC)          // 247 active
#define NWG 248                  // 8 x 31 (last wg idle)
#define XSTR 608                 // halves per A row: [x 300 | h 300 | pad 8]
#define WLS 616                  // LDS W col stride (halves)
#define BROWS 4160
#define BUFELT ((size_t)BROWS * XSTR)   // halves per slot (5.06 MB)

typedef _Float16 f16;
typedef _Float16 f16x8 __attribute__((ext_vector_type(8)));
typedef float    f32x4 __attribute__((ext_vector_type(4)));

__device__ __forceinline__ float sigm(float x) { return 1.0f / (1.0f + __expf(-x)); }
__device__ __forceinline__ float tanh_f(float x) {
    float ax = fabsf(x);
    float e = __expf(-2.0f * ax);
    return copysignf((1.0f - e) / (1.0f + e), x);
}
__device__ __forceinline__ f16x8 pack8(float4 a, float4 b) {
    f16x8 v;
    v[0] = (f16)a.x; v[1] = (f16)a.y; v[2] = (f16)a.z; v[3] = (f16)a.w;
    v[4] = (f16)b.x; v[5] = (f16)b.y; v[6] = (f16)b.z; v[7] = (f16)b.w;
    return v;
}

__global__ __launch_bounds__(256, 1)
void lstm_ws(const int* __restrict__ cap, const int* __restrict__ cap_len,
             const float* __restrict__ embed,
             const float* __restrict__ Wih, const float* __restrict__ Whh,
             const float* __restrict__ bih, const float* __restrict__ bhh,
             const float* __restrict__ v_wn, const float* __restrict__ g_wn,
             const float* __restrict__ b_cls,
             f16* __restrict__ bufs, int depth,
             unsigned* __restrict__ bar, float* __restrict__ out)
{
    __shared__ f16 Wl[64 * WLS];     // 78.8 KB stationary weights (fused K)
    __shared__ int capS[17][TT];
    __shared__ float scaleS[2];

    const int tid = threadIdx.x;
    const int b   = blockIdx.x;
    const int L   = (b & 7) * 31 + (b >> 3);   // XCD-chunked logical id
    if (L >= NACT) return;                     // groups are independent: just exit

    const int mb = L / NB;
    const int nb = L - mb * NB;
    const int mrow0 = mb * 320;
    const int wv = tid >> 6, ln = tid & 63, c = ln & 15, kg = ln >> 4;

    unsigned* flags = bar + mb * 1024;         // group flag base; wg flag at +nb*32

    // entry acquire-inv: drop any stale cached lines from a previous replay
    if (tid == 0)
        (void)__hip_atomic_load(flags, __ATOMIC_ACQUIRE, __HIP_MEMORY_SCOPE_AGENT);

    // ---- W block -> LDS: col=g*16+cc, k = [0,300)=Wih | [300,600)=Whh | 0 ----
    for (int u = tid; u < 64 * 76; u += 256) {
        int col = u / 76, k8 = u - col * 76;
        int g = col >> 4, cc = col & 15;
        int jh0 = nb * 16 + cc;
        int j = g * 300 + jh0;
        f16x8 v;
        #pragma unroll
        for (int i = 0; i < 8; ++i) {
            int kk = k8 * 8 + i;
            float x = 0.f;
            if (jh0 < 300) {
                if (kk < 300)      x = Wih[(size_t)j * 300 + kk];
                else if (kk < 600) x = Whh[(size_t)j * 300 + (kk - 300)];
            }
            v[i] = (f16)x;
        }
        *(f16x8*)&Wl[col * WLS + k8 * 8] = v;
    }

    // tokens for the 17 rows this wg stages within its mb block
    const int srow0 = nb * 17;
    for (int u = tid; u < 17 * TT; u += 256) {
        int rl = u / TT, t = u - rl * TT;
        int grow = mrow0 + srow0 + rl;
        capS[rl][t] = (srow0 + rl < 320 && grow < 4096) ? cap[(size_t)grow * TT + t] : 0;
    }
    if (tid < 2) {
        float s = 0.f;
        for (int k = 0; k < 300; ++k) { float v = v_wn[tid * 300 + k]; s += v * v; }
        scaleS[tid] = g_wn[tid] * rsqrtf(s);
    }
    __syncthreads();

    // ---- x staging: embed[tok] fp32 -> fp16 into a slot's x region ----
    auto stage_x = [&](int t, f16* bufn) {
        for (int u = tid; u < 17 * 38; u += 256) {
            int rl = u / 38, ch = u - rl * 38;
            int lrow = srow0 + rl, grow = mrow0 + lrow;
            if (lrow >= 320 || grow >= 4096) continue;
            const float* er = embed + (size_t)capS[rl][t] * 300;
            f16* dst = bufn + (size_t)grow * XSTR;
            int k0 = ch * 8;
            if (ch < 37) {
                float4 a = *(const float4*)(er + k0);
                float4 bb = *(const float4*)(er + k0 + 4);
                *(f16x8*)(dst + k0) = pack8(a, bb);
            } else {
                float4 a = *(const float4*)(er + 296);
                f16* d2 = dst + 296;
                d2[0] = (f16)a.x; d2[1] = (f16)a.y; d2[2] = (f16)a.z; d2[3] = (f16)a.w;
            }
        }
    };

    // ---- RMW-free group barrier ----
    auto arrive = [&](unsigned ph) {
        __syncthreads();   // all waves' stores complete (vmcnt 0)
        if (tid == 0)      // release: wbl2 (dirty L2 -> LLC), then flag store
            __hip_atomic_store(flags + nb * 32, ph, __ATOMIC_RELEASE,
                               __HIP_MEMORY_SCOPE_AGENT);
    };
    auto wait = [&](unsigned ph, bool inv) {
        if (tid < NB) {
            while (__hip_atomic_load(flags + tid * 32, __ATOMIC_RELAXED,
                                     __HIP_MEMORY_SCOPE_AGENT) < ph)
                __builtin_amdgcn_s_sleep(1);
        }
        if (inv && tid == 0)   // slot reuse (depth<23): invalidate stale lines
            (void)__hip_atomic_load(flags, __ATOMIC_ACQUIRE,
                                    __HIP_MEMORY_SCOPE_AGENT);
        __syncthreads();
    };

    // per-lane constants
    int aoff[5];
    #pragma unroll
    for (int m = 0; m < 5; ++m)
        aoff[m] = (mrow0 + (wv * 5 + m) * 16 + c) * XSTR + kg * 8;
    int bbase[4];
    #pragma unroll
    for (int g = 0; g < 4; ++g) bbase[g] = (g * 16 + c) * WLS + kg * 8;

    const int jh = nb * 16 + c;
    float bias[4];
    #pragma unroll
    for (int g = 0; g < 4; ++g) {
        float bv = 0.f;
        if (jh < 300) { int j = g * 300 + jh; bv = bih[j] + bhh[j]; }
        bias[g] = bv;
    }
    int lenr[5][4];
    #pragma unroll
    for (int m = 0; m < 5; ++m) {
        int rb = mrow0 + (wv * 5 + m) * 16 + kg * 4;
        #pragma unroll
        for (int rg = 0; rg < 4; ++rg) {
            int row = rb + rg;
            lenr[m][rg] = (row < 4096) ? cap_len[row] : 0;
        }
    }

    float cst[5][4] = {};
    float hreg[5][4] = {};

    stage_x(0, bufs);          // slot 0 (h region pre-zeroed by host memset)
    arrive(1);
    wait(1, false);            // depth >= 2: slot 0 is first-use

    #pragma unroll 1
    for (int t = 0; t < STEPS; ++t) {
        const f16* bufc = bufs + (size_t)(t % depth) * BUFELT;
        f16*       bufn = bufs + (size_t)((t + 1) % depth) * BUFELT;

        f32x4 acc[5][4];
        #pragma unroll
        for (int m = 0; m < 5; ++m)
            #pragma unroll
            for (int g = 0; g < 4; ++g) {
                float bv = bias[g];
                f32x4 b4 = {bv, bv, bv, bv};
                acc[m][g] = b4;
            }

        // fused K=608 GEMM: A = [x|h] from slot, B = LDS W
        #pragma unroll
        for (int kt = 0; kt < 19; ++kt) {
            f16x8 av[5];
            #pragma unroll
            for (int m = 0; m < 5; ++m)
                av[m] = *(const f16x8*)(bufc + aoff[m] + kt * 32);
            #pragma unroll
            for (int g = 0; g < 4; ++g) {
                f16x8 bv = *(const f16x8*)&Wl[bbase[g] + kt * 32];
                #pragma unroll
                for (int m = 0; m < 5; ++m)
                    acc[m][g] = __builtin_amdgcn_mfma_f32_16x16x32_f16(av[m], bv, acc[m][g], 0, 0, 0);
            }
        }

        // gate nonlinearities + state update (i/f/g/o same-lane acc regs)
        #pragma unroll
        for (int m = 0; m < 5; ++m) {
            #pragma unroll
            for (int rg = 0; rg < 4; ++rg) {
                bool upd = (t < lenr[m][rg]);
                float iv = sigm(acc[m][0][rg]);
                float fv = sigm(acc[m][1][rg]);
                float gv = tanh_f(acc[m][2][rg]);
                float ov = sigm(acc[m][3][rg]);
                float cn = fv * cst[m][rg] + iv * gv;
                cn = upd ? cn : cst[m][rg];
                cst[m][rg] = cn;
                float hn = ov * tanh_f(cn);
                hreg[m][rg] = upd ? hn : hreg[m][rg];
            }
            if (jh < 300) {
                int rb = mrow0 + (wv * 5 + m) * 16 + kg * 4;
                #pragma unroll
                for (int rg = 0; rg < 4; ++rg)
                    bufn[(size_t)(rb + rg) * XSTR + 300 + jh] = (f16)hreg[m][rg];
            }
        }

        if (t + 1 < STEPS) stage_x(t + 1, bufn);
        arrive((unsigned)(t + 2));
        wait((unsigned)(t + 2), (t + 1) >= depth);
    }

    // ---- head: OWN group's rows only (all h produced by this group) ----
    const f16* hb = bufs + (size_t)(STEPS % depth) * BUFELT;
    for (int u = tid; u < 34; u += 256) {      // 17 rows x 2 classes
        int rl = u >> 1, cls = u & 1;
        int lrow = srow0 + rl, grow = mrow0 + lrow;
        if (lrow >= 320 || grow >= 4096) continue;
        float sc = scaleS[cls];
        const float* vr = v_wn + cls * 300;
        const f16* hr = hb + (size_t)grow * XSTR + 300;
        float s = 0.f;
        #pragma unroll 4
        for (int k = 0; k < 300; ++k) s += vr[k] * (float)hr[k];
        out[(size_t)grow * 2 + cls] = sc * s + b_cls[cls];
    }
}

extern "C" void kernel_launch(void* const* d_in, const int* in_sizes, int n_in,
                              void* d_out, int out_size, void* d_ws, size_t ws_size,
                              hipStream_t stream) {
    const int*   cap     = (const int*)  d_in[0];
    const int*   cap_len = (const int*)  d_in[1];
    const float* embed   = (const float*)d_in[2];
    const float* W_ih    = (const float*)d_in[3];
    const float* W_hh    = (const float*)d_in[4];
    const float* b_ih    = (const float*)d_in[5];
    const float* b_hh    = (const float*)d_in[6];
    const float* v_wn    = (const float*)d_in[7];
    const float* g_wn    = (const float*)d_in[8];
    const float* b_cls   = (const float*)d_in[9];
    float* out = (float*)d_out;

    unsigned* bar = (unsigned*)d_ws;
    f16* bufs = (f16*)((char*)d_ws + 65536);
    size_t slot_bytes = BUFELT * sizeof(f16);          // 5,058,560
    int depth = (int)((ws_size > 65536 ? ws_size - 65536 : 0) / slot_bytes);
    if (depth > STEPS + 1) depth = STEPS + 1;          // 23 = fully virgin
    if (depth < 2) depth = 2;                          // rounds 3-6 footprint

    hipMemsetAsync(bar, 0, 65536, stream);             // flags
    hipMemsetAsync(bufs, 0, slot_bytes, stream);       // slot 0 (h_0 = 0)

    lstm_ws<<<NWG, 256, 0, stream>>>(cap, cap_len, embed, W_ih, W_hh, b_ih, b_hh,
                                     v_wn, g_wn, b_cls, bufs, depth, bar, out);
}

// Round 8
// 490.629 us; speedup vs baseline: 1.5960x; 1.1077x over previous
//
#include <hip/hip_runtime.h>
#include <hip/hip_fp16.h>

// Weight-stationary LSTM classifier, XCD-aligned groups + 8-wave wgs.
// B=4096, T=22, E=H=300. 8 groups (512 rows) x 19 wgs (16 jh x 4 gates);
// grid 152, grp = b&7 pins each group to one XCD (perf heuristic only --
// correctness is agent-scope). W block (64 cols x 608 k fp16 = 79KB)
// LDS-stationary. Per step, fused K=608 GEMM in two halves:
//   x-part (kt 0..8, k<288): runs BEFORE the flag wait (x staged 2 steps
//     ahead when depth>=3), hiding barrier latency;
//   h-part (kt 9..18): after wait. Gates i/f/g/o same-lane; h fp16 to
//     slot t+1; x fp16 staged to slot t+2; RMW-free store-release flags
//     (19 per group, 128B apart), lanes 0..18 poll relaxed.
// Slots rotate depth D (from ws_size, 2..23); virgin slots skip buffer_inv;
// reused slots get an acquire-inv. Entry acquire-inv for graph replay.
// d_ws: [0,64KB) flags, then D x 4096x608 fp16 slots (4.98 MB each).

#define TT 22
#define STEPS 22
#define NB 19
#define NGRP 8
#define GROWS 512
#define NWG (NB * NGRP)          // 152
#define NTHR 512
#define XSTR 608                 // halves per A row: [x 300 | h 300 | pad 8]
#define WLS 616                  // LDS W col stride (halves)
#define BROWS 4096
#define BUFELT ((size_t)BROWS * XSTR)   // halves per slot
#define SROWS 27                 // staging rows per wg (ceil 512/19)

typedef _Float16 f16;
typedef _Float16 f16x8 __attribute__((ext_vector_type(8)));
typedef float    f32x4 __attribute__((ext_vector_type(4)));

__device__ __forceinline__ float sigm(float x) { return 1.0f / (1.0f + __expf(-x)); }
__device__ __forceinline__ float tanh_f(float x) {
    float ax = fabsf(x);
    float e = __expf(-2.0f * ax);
    return copysignf((1.0f - e) / (1.0f + e), x);
}
__device__ __forceinline__ f16x8 pack8(float4 a, float4 b) {
    f16x8 v;
    v[0] = (f16)a.x; v[1] = (f16)a.y; v[2] = (f16)a.z; v[3] = (f16)a.w;
    v[4] = (f16)b.x; v[5] = (f16)b.y; v[6] = (f16)b.z; v[7] = (f16)b.w;
    return v;
}

__global__ __launch_bounds__(NTHR, 2)
void lstm_ws(const int* __restrict__ cap, const int* __restrict__ cap_len,
             const float* __restrict__ embed,
             const float* __restrict__ Wih, const float* __restrict__ Whh,
             const float* __restrict__ bih, const float* __restrict__ bhh,
             const float* __restrict__ v_wn, const float* __restrict__ g_wn,
             const float* __restrict__ b_cls,
             f16* __restrict__ bufs, int depth,
             unsigned* __restrict__ bar, float* __restrict__ out)
{
    __shared__ f16 Wl[64 * WLS];     // 78.8 KB stationary weights
    __shared__ int capS[SROWS][TT];
    __shared__ float scaleS[2];

    const int tid = threadIdx.x;
    const int b   = blockIdx.x;
    const int grp = b & 7;           // group == XCD (round-robin heuristic)
    const int nb  = b >> 3;          // 0..18 jh-tile
    const int mrow0 = grp * GROWS;
    const int wv = tid >> 6, ln = tid & 63, c = ln & 15, kg = ln >> 4;
    const bool ahead2 = (depth >= 3);

    unsigned* flags = bar + grp * 1024;   // wg flag at + nb*32 (128B lines)

    // entry acquire-inv: drop stale cached lines from a previous replay
    if (tid == 0)
        (void)__hip_atomic_load(flags, __ATOMIC_ACQUIRE, __HIP_MEMORY_SCOPE_AGENT);

    auto slot = [&](int n) { return bufs + (size_t)(n % depth) * BUFELT; };

    // ---- W block -> LDS: col=g*16+cc, k = [0,300)=Wih | [300,600)=Whh | 0 ----
    for (int u = tid; u < 64 * 76; u += NTHR) {
        int col = u / 76, k8 = u - col * 76;
        int g = col >> 4, cc = col & 15;
        int jh0 = nb * 16 + cc;
        int j = g * 300 + jh0;
        f16x8 v;
        #pragma unroll
        for (int i = 0; i < 8; ++i) {
            int kk = k8 * 8 + i;
            float x = 0.f;
            if (jh0 < 300) {
                if (kk < 300)      x = Wih[(size_t)j * 300 + kk];
                else if (kk < 600) x = Whh[(size_t)j * 300 + (kk - 300)];
            }
            v[i] = (f16)x;
        }
        *(f16x8*)&Wl[col * WLS + k8 * 8] = v;
    }

    // staging rows for this wg within its group
    const int srow0 = nb * SROWS;
    const int nr = (GROWS - srow0) < SROWS ? (GROWS - srow0) : SROWS;  // 27 or 26
    for (int u = tid; u < SROWS * TT; u += NTHR) {
        int rl = u / TT, t = u - rl * TT;
        if (rl < nr) capS[rl][t] = cap[(size_t)(mrow0 + srow0 + rl) * TT + t];
    }
    if (tid < 2) {
        float s = 0.f;
        for (int k = 0; k < 300; ++k) { float v = v_wn[tid * 300 + k]; s += v * v; }
        scaleS[tid] = g_wn[tid] * rsqrtf(s);
    }
    __syncthreads();

    // ---- x staging: embed[tok] fp32 -> fp16 into a slot's x region ----
    auto stage_x = [&](int t, f16* bufn) {
        for (int u = tid; u < nr * 38; u += NTHR) {
            int rl = u / 38, ch = u - rl * 38;
            int grow = mrow0 + srow0 + rl;
            const float* er = embed + (size_t)capS[rl][t] * 300;
            f16* dst = bufn + (size_t)grow * XSTR;
            int k0 = ch * 8;
            if (ch < 37) {
                float4 a = *(const float4*)(er + k0);
                float4 bb = *(const float4*)(er + k0 + 4);
                *(f16x8*)(dst + k0) = pack8(a, bb);
            } else {
                float4 a = *(const float4*)(er + 296);
                f16* d2 = dst + 296;
                d2[0] = (f16)a.x; d2[1] = (f16)a.y; d2[2] = (f16)a.z; d2[3] = (f16)a.w;
            }
        }
    };

    // ---- RMW-free group barrier (19 wgs) ----
    auto arrive = [&](unsigned ph) {
        __syncthreads();   // all waves' stores complete
        if (tid == 0)      // release: wbl2 then flag store
            __hip_atomic_store(flags + nb * 32, ph, __ATOMIC_RELEASE,
                               __HIP_MEMORY_SCOPE_AGENT);
    };
    auto wait = [&](unsigned ph, bool inv) {
        if (tid < NB) {
            while (__hip_atomic_load(flags + tid * 32, __ATOMIC_RELAXED,
                                     __HIP_MEMORY_SCOPE_AGENT) < ph)
                __builtin_amdgcn_s_sleep(1);
        }
        if (inv && tid == 0)   // slot reuse: invalidate stale clean lines
            (void)__hip_atomic_load(flags, __ATOMIC_ACQUIRE,
                                    __HIP_MEMORY_SCOPE_AGENT);
        __syncthreads();
    };

    // per-lane constants
    int aoff[4];
    #pragma unroll
    for (int m = 0; m < 4; ++m)
        aoff[m] = (mrow0 + wv * 64 + m * 16 + c) * XSTR + kg * 8;
    int bbase[4];
    #pragma unroll
    for (int g = 0; g < 4; ++g) bbase[g] = (g * 16 + c) * WLS + kg * 8;

    const int jh = nb * 16 + c;
    float bias[4];
    #pragma unroll
    for (int g = 0; g < 4; ++g) {
        float bv = 0.f;
        if (jh < 300) { int j = g * 300 + jh; bv = bih[j] + bhh[j]; }
        bias[g] = bv;
    }
    int lenr[4][4];
    #pragma unroll
    for (int m = 0; m < 4; ++m) {
        int rb = mrow0 + wv * 64 + m * 16 + kg * 4;
        #pragma unroll
        for (int rg = 0; rg < 4; ++rg) lenr[m][rg] = cap_len[rb + rg];
    }

    float cst[4][4] = {};
    float hreg[4][4] = {};
    f32x4 acc[4][4];

    auto xpart = [&](const f16* bufc) {   // kt 0..8 (k < 288): x only
        #pragma unroll
        for (int kt = 0; kt < 9; ++kt) {
            f16x8 av[4];
            #pragma unroll
            for (int m = 0; m < 4; ++m)
                av[m] = *(const f16x8*)(bufc + aoff[m] + kt * 32);
            #pragma unroll
            for (int g = 0; g < 4; ++g) {
                f16x8 bv = *(const f16x8*)&Wl[bbase[g] + kt * 32];
                #pragma unroll
                for (int m = 0; m < 4; ++m)
                    acc[m][g] = __builtin_amdgcn_mfma_f32_16x16x32_f16(av[m], bv, acc[m][g], 0, 0, 0);
            }
        }
    };
    auto hpart = [&](const f16* bufc) {   // kt 9..18 (k 288..607): straddle + h
        #pragma unroll
        for (int kt = 9; kt < 19; ++kt) {
            f16x8 av[4];
            #pragma unroll
            for (int m = 0; m < 4; ++m)
                av[m] = *(const f16x8*)(bufc + aoff[m] + kt * 32);
            #pragma unroll
            for (int g = 0; g < 4; ++g) {
                f16x8 bv = *(const f16x8*)&Wl[bbase[g] + kt * 32];
                #pragma unroll
                for (int m = 0; m < 4; ++m)
                    acc[m][g] = __builtin_amdgcn_mfma_f32_16x16x32_f16(av[m], bv, acc[m][g], 0, 0, 0);
            }
        }
    };

    // prologue: stage x(0) (+x(1) if deep enough); slot0 h-region is zeroed
    stage_x(0, slot(0));
    if (ahead2) stage_x(1, slot(1));
    arrive(1);
    wait(1, false);

    #pragma unroll 1
    for (int t = 0; t < STEPS; ++t) {
        const f16* bufc = slot(t);
        #pragma unroll
        for (int m = 0; m < 4; ++m)
            #pragma unroll
            for (int g = 0; g < 4; ++g) {
                float bv = bias[g];
                f32x4 b4 = {bv, bv, bv, bv};
                acc[m][g] = b4;
            }

        if (ahead2) {
            xpart(bufc);                              // x released >=1 step ago
            wait((unsigned)(t + 1), (t + 1) >= depth);
        } else {
            wait((unsigned)(t + 1), (t + 1) >= depth);
            xpart(bufc);
        }
        hpart(bufc);

        // gate nonlinearities + state update (i/f/g/o same-lane acc regs)
        f16* bufn = slot(t + 1);
        #pragma unroll
        for (int m = 0; m < 4; ++m) {
            #pragma unroll
            for (int rg = 0; rg < 4; ++rg) {
                bool upd = (t < lenr[m][rg]);
                float iv = sigm(acc[m][0][rg]);
                float fv = sigm(acc[m][1][rg]);
                float gv = tanh_f(acc[m][2][rg]);
                float ov = sigm(acc[m][3][rg]);
                float cn = fv * cst[m][rg] + iv * gv;
                cn = upd ? cn : cst[m][rg];
                cst[m][rg] = cn;
                float hn = ov * tanh_f(cn);
                hreg[m][rg] = upd ? hn : hreg[m][rg];
            }
            if (jh < 300) {
                int rb = mrow0 + wv * 64 + m * 16 + kg * 4;
                #pragma unroll
                for (int rg = 0; rg < 4; ++rg)
                    bufn[(size_t)(rb + rg) * XSTR + 300 + jh] = (f16)hreg[m][rg];
            }
        }

        if (ahead2) { if (t + 2 < STEPS) stage_x(t + 2, slot(t + 2)); }
        else        { if (t + 1 < STEPS) stage_x(t + 1, slot(t + 1)); }
        arrive((unsigned)(t + 2));
    }

    wait((unsigned)(STEPS + 1), STEPS >= depth);   // all h(22) visible

    // ---- head: this wg's staged rows, 2 classes ----
    const f16* hb = slot(STEPS);
    for (int u = tid; u < nr * 2; u += NTHR) {
        int rl = u >> 1, cls = u & 1;
        int grow = mrow0 + srow0 + rl;
        float sc = scaleS[cls];
        const float* vr = v_wn + cls * 300;
        const f16* hr = hb + (size_t)grow * XSTR + 300;
        float s = 0.f;
        #pragma unroll 4
        for (int k = 0; k < 300; ++k) s += vr[k] * (float)hr[k];
        out[(size_t)grow * 2 + cls] = sc * s + b_cls[cls];
    }
}

extern "C" void kernel_launch(void* const* d_in, const int* in_sizes, int n_in,
                              void* d_out, int out_size, void* d_ws, size_t ws_size,
                              hipStream_t stream) {
    const int*   cap     = (const int*)  d_in[0];
    const int*   cap_len = (const int*)  d_in[1];
    const float* embed   = (const float*)d_in[2];
    const float* W_ih    = (const float*)d_in[3];
    const float* W_hh    = (const float*)d_in[4];
    const float* b_ih    = (const float*)d_in[5];
    const float* b_hh    = (const float*)d_in[6];
    const float* v_wn    = (const float*)d_in[7];
    const float* g_wn    = (const float*)d_in[8];
    const float* b_cls   = (const float*)d_in[9];
    float* out = (float*)d_out;

    unsigned* bar = (unsigned*)d_ws;
    f16* bufs = (f16*)((char*)d_ws + 65536);
    size_t slot_bytes = BUFELT * sizeof(f16);          // 4,980,736
    int depth = (int)((ws_size > 65536 ? ws_size - 65536 : 0) / slot_bytes);
    if (depth > STEPS + 1) depth = STEPS + 1;          // 23 = fully virgin
    if (depth < 2) depth = 2;                          // proven 10.1MB footprint

    hipMemsetAsync(bar, 0, 65536, stream);             // flags
    hipMemsetAsync(bufs, 0, slot_bytes, stream);       // slot 0 (h_0 = 0)

    lstm_ws<<<NWG, NTHR, 0, stream>>>(cap, cap_len, embed, W_ih, W_hh, b_ih, b_hh,
                                      v_wn, g_wn, b_cls, bufs, depth, bar, out);
}

// Round 9
// 431.747 us; speedup vs baseline: 1.8136x; 1.1364x over previous
//
#include <hip/hip_runtime.h>
#include <hip/hip_fp16.h>

// Weight-stationary LSTM classifier, XCD-aligned groups + same-XCD fast sync.
// B=4096, T=22, E=H=300. 8 groups (512 rows) x 19 wgs (16 jh x 4 gates);
// grid 152, grp = b&7. W block (64 cols x 608 k fp16 = 79KB) LDS-stationary.
// Sync: each wg publishes its physical XCD id (s_getreg HW_REG_XCC_ID); after
// a one-time full-fence barrier each group computes fastp = all-19-same-XCD.
//   fast path: arrive = syncthreads + RELAXED agent flag store (no buffer_wbl2
//     -> h/x stay DIRTY in the shared XCD L2; consumers hit them at ~200cyc);
//     wait = poll relaxed + acquire fence only on slot reuse (buffer_inv
//     preserves dirty lines, cleans stale L1).
//   slow path (placement fallback): round-8 release/acquire protocol.
// Per step: x-part GEMM (kt 0..8) runs BEFORE the wait (x staged 2 ahead when
// depth>=3); h-part after. Gates i/f/g/o same-lane; h fp16 to slot t+1.
// d_ws: [0,64KB) flags+ids, then depth x 4096x608 fp16 slots (4.98 MB each).

#define TT 22
#define STEPS 22
#define NB 19
#define NGRP 8
#define GROWS 512
#define NWG (NB * NGRP)          // 152
#define NTHR 512
#define XSTR 608                 // halves per A row: [x 300 | h 300 | pad 8]
#define WLS 616                  // LDS W col stride (halves)
#define BROWS 4096
#define BUFELT ((size_t)BROWS * XSTR)   // halves per slot
#define SROWS 27                 // staging rows per wg (ceil 512/19)

typedef _Float16 f16;
typedef _Float16 f16x8 __attribute__((ext_vector_type(8)));
typedef float    f32x4 __attribute__((ext_vector_type(4)));

__device__ __forceinline__ float sigm(float x) { return 1.0f / (1.0f + __expf(-x)); }
__device__ __forceinline__ float tanh_f(float x) {
    float ax = fabsf(x);
    float e = __expf(-2.0f * ax);
    return copysignf((1.0f - e) / (1.0f + e), x);
}
__device__ __forceinline__ f16x8 pack8(float4 a, float4 b) {
    f16x8 v;
    v[0] = (f16)a.x; v[1] = (f16)a.y; v[2] = (f16)a.z; v[3] = (f16)a.w;
    v[4] = (f16)b.x; v[5] = (f16)b.y; v[6] = (f16)b.z; v[7] = (f16)b.w;
    return v;
}

__global__ __launch_bounds__(NTHR, 2)
void lstm_ws(const int* __restrict__ cap, const int* __restrict__ cap_len,
             const float* __restrict__ embed,
             const float* __restrict__ Wih, const float* __restrict__ Whh,
             const float* __restrict__ bih, const float* __restrict__ bhh,
             const float* __restrict__ v_wn, const float* __restrict__ g_wn,
             const float* __restrict__ b_cls,
             f16* __restrict__ bufs, int depth,
             unsigned* __restrict__ bar, float* __restrict__ out)
{
    __shared__ f16 Wl[64 * WLS];     // 78.8 KB stationary weights
    __shared__ int capS[SROWS][TT];
    __shared__ float scaleS[2];
    __shared__ unsigned idsS[NB];

    const int tid = threadIdx.x;
    const int b   = blockIdx.x;
    const int grp = b & 7;           // group; fast path verifies == physical XCD
    const int nb  = b >> 3;          // 0..18 jh-tile
    const int mrow0 = grp * GROWS;
    const int wv = tid >> 6, ln = tid & 63, c = ln & 15, kg = ln >> 4;
    const bool ahead2 = (depth >= 3);

    unsigned* flags = bar + grp * 1024;        // wg flag at + nb*32 (128B lines)
    unsigned* ids   = bar + grp * 1024 + 768;  // 19 published XCD ids

    // entry acquire: drop stale cached lines from a previous replay
    if (tid == 0)
        (void)__hip_atomic_load(flags, __ATOMIC_ACQUIRE, __HIP_MEMORY_SCOPE_AGENT);

    // publish this wg's physical XCD id [measured: learn_hip m09]
    unsigned xcc;
    asm volatile("s_getreg_b32 %0, hwreg(HW_REG_XCC_ID)" : "=s"(xcc));
    if (tid == 0)
        __hip_atomic_store(ids + nb, xcc + 1u, __ATOMIC_RELAXED,
                           __HIP_MEMORY_SCOPE_AGENT);

    auto slot = [&](int n) { return bufs + (size_t)(n % depth) * BUFELT; };

    // ---- W block -> LDS: col=g*16+cc, k = [0,300)=Wih | [300,600)=Whh | 0 ----
    for (int u = tid; u < 64 * 76; u += NTHR) {
        int col = u / 76, k8 = u - col * 76;
        int g = col >> 4, cc = col & 15;
        int jh0 = nb * 16 + cc;
        int j = g * 300 + jh0;
        f16x8 v;
        #pragma unroll
        for (int i = 0; i < 8; ++i) {
            int kk = k8 * 8 + i;
            float x = 0.f;
            if (jh0 < 300) {
                if (kk < 300)      x = Wih[(size_t)j * 300 + kk];
                else if (kk < 600) x = Whh[(size_t)j * 300 + (kk - 300)];
            }
            v[i] = (f16)x;
        }
        *(f16x8*)&Wl[col * WLS + k8 * 8] = v;
    }

    // staging rows for this wg within its group
    const int srow0 = nb * SROWS;
    const int nr = (GROWS - srow0) < SROWS ? (GROWS - srow0) : SROWS;  // 27 or 26
    for (int u = tid; u < SROWS * TT; u += NTHR) {
        int rl = u / TT, t = u - rl * TT;
        if (rl < nr) capS[rl][t] = cap[(size_t)(mrow0 + srow0 + rl) * TT + t];
    }
    if (tid < 2) {
        float s = 0.f;
        for (int k = 0; k < 300; ++k) { float v = v_wn[tid * 300 + k]; s += v * v; }
        scaleS[tid] = g_wn[tid] * rsqrtf(s);
    }
    __syncthreads();

    // ---- x staging: embed[tok] fp32 -> fp16 into a slot's x region ----
    auto stage_x = [&](int t, f16* bufn) {
        for (int u = tid; u < nr * 38; u += NTHR) {
            int rl = u / 38, ch = u - rl * 38;
            int grow = mrow0 + srow0 + rl;
            const float* er = embed + (size_t)capS[rl][t] * 300;
            f16* dst = bufn + (size_t)grow * XSTR;
            int k0 = ch * 8;
            if (ch < 37) {
                float4 a = *(const float4*)(er + k0);
                float4 bb = *(const float4*)(er + k0 + 4);
                *(f16x8*)(dst + k0) = pack8(a, bb);
            } else {
                float4 a = *(const float4*)(er + 296);
                f16* d2 = dst + 296;
                d2[0] = (f16)a.x; d2[1] = (f16)a.y; d2[2] = (f16)a.z; d2[3] = (f16)a.w;
            }
        }
    };

    // ---- group barrier: arrive (rel: release->wbl2 / relaxed: none) ----
    auto arrive = [&](unsigned ph, bool rel) {
        __syncthreads();   // all waves' vmem stores drained (vmcnt 0) -> in L2
        if (tid == 0) {
            if (rel)
                __hip_atomic_store(flags + nb * 32, ph, __ATOMIC_RELEASE,
                                   __HIP_MEMORY_SCOPE_AGENT);
            else
                __hip_atomic_store(flags + nb * 32, ph, __ATOMIC_RELAXED,
                                   __HIP_MEMORY_SCOPE_AGENT);
        }
    };
    auto wait = [&](unsigned ph, bool fen) {
        if (tid < NB) {
            while (__hip_atomic_load(flags + tid * 32, __ATOMIC_RELAXED,
                                     __HIP_MEMORY_SCOPE_AGENT) < ph)
                __builtin_amdgcn_s_sleep(1);
        }
        if (fen)   // buffer_inv: clean lines + L1 dropped, DIRTY L2 preserved
            __builtin_amdgcn_fence(__ATOMIC_ACQUIRE, "agent");
        __syncthreads();
    };

    // per-lane constants
    int aoff[4];
    #pragma unroll
    for (int m = 0; m < 4; ++m)
        aoff[m] = (mrow0 + wv * 64 + m * 16 + c) * XSTR + kg * 8;
    int bbase[4];
    #pragma unroll
    for (int g = 0; g < 4; ++g) bbase[g] = (g * 16 + c) * WLS + kg * 8;

    const int jh = nb * 16 + c;
    float bias[4];
    #pragma unroll
    for (int g = 0; g < 4; ++g) {
        float bv = 0.f;
        if (jh < 300) { int j = g * 300 + jh; bv = bih[j] + bhh[j]; }
        bias[g] = bv;
    }
    int lenr[4][4];
    #pragma unroll
    for (int m = 0; m < 4; ++m) {
        int rb = mrow0 + wv * 64 + m * 16 + kg * 4;
        #pragma unroll
        for (int rg = 0; rg < 4; ++rg) lenr[m][rg] = cap_len[rb + rg];
    }

    float cst[4][4] = {};
    float hreg[4][4] = {};
    f32x4 acc[4][4];

    auto xpart = [&](const f16* bufc) {   // kt 0..8 (k < 288): x only
        #pragma unroll
        for (int kt = 0; kt < 9; ++kt) {
            f16x8 av[4];
            #pragma unroll
            for (int m = 0; m < 4; ++m)
                av[m] = *(const f16x8*)(bufc + aoff[m] + kt * 32);
            #pragma unroll
            for (int g = 0; g < 4; ++g) {
                f16x8 bv = *(const f16x8*)&Wl[bbase[g] + kt * 32];
                #pragma unroll
                for (int m = 0; m < 4; ++m)
                    acc[m][g] = __builtin_amdgcn_mfma_f32_16x16x32_f16(av[m], bv, acc[m][g], 0, 0, 0);
            }
        }
    };
    auto hpart = [&](const f16* bufc) {   // kt 9..18 (k 288..607): straddle + h
        #pragma unroll
        for (int kt = 9; kt < 19; ++kt) {
            f16x8 av[4];
            #pragma unroll
            for (int m = 0; m < 4; ++m)
                av[m] = *(const f16x8*)(bufc + aoff[m] + kt * 32);
            #pragma unroll
            for (int g = 0; g < 4; ++g) {
                f16x8 bv = *(const f16x8*)&Wl[bbase[g] + kt * 32];
                #pragma unroll
                for (int m = 0; m < 4; ++m)
                    acc[m][g] = __builtin_amdgcn_mfma_f32_16x16x32_f16(av[m], bv, acc[m][g], 0, 0, 0);
            }
        }
    };

    // prologue: stage x(0) (+x(1) if deep enough); slot0 h-region host-zeroed.
    // Setup barrier is FULL-FENCE both sides (publishes ids + x stages).
    stage_x(0, slot(0));
    if (ahead2) stage_x(1, slot(1));
    arrive(1, true);
    wait(1, true);

    // group placement vote: fast path only if all 19 wgs share one XCD
    if (tid < NB)
        idsS[tid] = __hip_atomic_load(ids + tid, __ATOMIC_RELAXED,
                                      __HIP_MEMORY_SCOPE_AGENT);
    __syncthreads();
    bool fastp = true;
    #pragma unroll 1
    for (int i = 1; i < NB; ++i) fastp = fastp && (idsS[i] == idsS[0]);

    #pragma unroll 1
    for (int t = 0; t < STEPS; ++t) {
        const f16* bufc = slot(t);
        #pragma unroll
        for (int m = 0; m < 4; ++m)
            #pragma unroll
            for (int g = 0; g < 4; ++g) {
                float bv = bias[g];
                f32x4 b4 = {bv, bv, bv, bv};
                acc[m][g] = b4;
            }

        bool reuse = (unsigned)(t + 1) >= (unsigned)depth;
        if (ahead2) {
            xpart(bufc);                   // x(t) released >=1 step ago
            wait((unsigned)(t + 1), reuse);
        } else {
            wait((unsigned)(t + 1), reuse);
            xpart(bufc);
        }
        hpart(bufc);

        // gate nonlinearities + state update (i/f/g/o same-lane acc regs)
        f16* bufn = slot(t + 1);
        #pragma unroll
        for (int m = 0; m < 4; ++m) {
            #pragma unroll
            for (int rg = 0; rg < 4; ++rg) {
                bool upd = (t < lenr[m][rg]);
                float iv = sigm(acc[m][0][rg]);
                float fv = sigm(acc[m][1][rg]);
                float gv = tanh_f(acc[m][2][rg]);
                float ov = sigm(acc[m][3][rg]);
                float cn = fv * cst[m][rg] + iv * gv;
                cn = upd ? cn : cst[m][rg];
                cst[m][rg] = cn;
                float hn = ov * tanh_f(cn);
                hreg[m][rg] = upd ? hn : hreg[m][rg];
            }
            if (jh < 300) {
                int rb = mrow0 + wv * 64 + m * 16 + kg * 4;
                #pragma unroll
                for (int rg = 0; rg < 4; ++rg)
                    bufn[(size_t)(rb + rg) * XSTR + 300 + jh] = (f16)hreg[m][rg];
            }
        }

        if (ahead2) { if (t + 2 < STEPS) stage_x(t + 2, slot(t + 2)); }
        else        { if (t + 1 < STEPS) stage_x(t + 1, slot(t + 1)); }
        arrive((unsigned)(t + 2), !fastp);
    }

    wait((unsigned)(STEPS + 1), true);   // all h(22) visible

    // ---- head: this wg's staged rows, 2 classes ----
    const f16* hb = slot(STEPS);
    for (int u = tid; u < nr * 2; u += NTHR) {
        int rl = u >> 1, cls = u & 1;
        int grow = mrow0 + srow0 + rl;
        float sc = scaleS[cls];
        const float* vr = v_wn + cls * 300;
        const f16* hr = hb + (size_t)grow * XSTR + 300;
        float s = 0.f;
        #pragma unroll 4
        for (int k = 0; k < 300; ++k) s += vr[k] * (float)hr[k];
        out[(size_t)grow * 2 + cls] = sc * s + b_cls[cls];
    }
}

extern "C" void kernel_launch(void* const* d_in, const int* in_sizes, int n_in,
                              void* d_out, int out_size, void* d_ws, size_t ws_size,
                              hipStream_t stream) {
    const int*   cap     = (const int*)  d_in[0];
    const int*   cap_len = (const int*)  d_in[1];
    const float* embed   = (const float*)d_in[2];
    const float* W_ih    = (const float*)d_in[3];
    const float* W_hh    = (const float*)d_in[4];
    const float* b_ih    = (const float*)d_in[5];
    const float* b_hh    = (const float*)d_in[6];
    const float* v_wn    = (const float*)d_in[7];
    const float* g_wn    = (const float*)d_in[8];
    const float* b_cls   = (const float*)d_in[9];
    float* out = (float*)d_out;

    unsigned* bar = (unsigned*)d_ws;
    f16* bufs = (f16*)((char*)d_ws + 65536);
    size_t slot_bytes = BUFELT * sizeof(f16);          // 4,980,736
    int depth = (int)((ws_size > 65536 ? ws_size - 65536 : 0) / slot_bytes);
    if (depth > STEPS + 1) depth = STEPS + 1;          // 23 = fully virgin
    if (depth < 2) depth = 2;                          // proven footprint

    hipMemsetAsync(bar, 0, 65536, stream);             // flags + ids
    hipMemsetAsync(bufs, 0, slot_bytes, stream);       // slot 0 (h_0 = 0)

    lstm_ws<<<NWG, NTHR, 0, stream>>>(cap, cap_len, embed, W_ih, W_hh, b_ih, b_hh,
                                      v_wn, g_wn, b_cls, bufs, depth, bar, out);
}

// Round 10
// 431.418 us; speedup vs baseline: 1.8150x; 1.0008x over previous
//
#include <hip/hip_runtime.h>
#include <hip/hip_fp16.h>

// LSTM classifier, tiered on ws_size.
// TIER A (ws >= 282.2 MB): decouple x from the recurrence.
//   k1 stage_x_all: x[t][4096][320] fp16 for all 22 steps (pure parallel).
//   k2 gx_pre: per-wg gx[t][64cols][512rows] fp16 = bias + x_t @ Wih
//      (152 wgs x 1024 thr, Wih block in LDS, x panels L2-shared per XCD).
//   k3 lstm_rec: recurrent loop, Whh-only LDS (42KB -> 16 waves, 4/SIMD).
//      Per step: prefetch own gx(t) (no dep, before wait) -> wait -> h@Whh
//      (10 kt) -> gates -> h-store -> arrive. Round-9 flag protocol:
//      RMW-free store-release flags, same-XCD fastpath vote via XCC_ID.
// TIER C (smaller ws): round-9 kernel verbatim (431 us, known good).

#define TT 22
#define STEPS 22
#define NB 19
#define NGRP 8
#define GROWS 512
#define NWG (NB * NGRP)          // 152

typedef _Float16 f16;
typedef _Float16 f16x4 __attribute__((ext_vector_type(4)));
typedef _Float16 f16x8 __attribute__((ext_vector_type(8)));
typedef float    f32x4 __attribute__((ext_vector_type(4)));

__device__ __forceinline__ float sigm(float x) { return 1.0f / (1.0f + __expf(-x)); }
__device__ __forceinline__ float tanh_f(float x) {
    float ax = fabsf(x);
    float e = __expf(-2.0f * ax);
    return copysignf((1.0f - e) / (1.0f + e), x);
}
__device__ __forceinline__ f16x8 pack8(float4 a, float4 b) {
    f16x8 v;
    v[0] = (f16)a.x; v[1] = (f16)a.y; v[2] = (f16)a.z; v[3] = (f16)a.w;
    v[4] = (f16)b.x; v[5] = (f16)b.y; v[6] = (f16)b.z; v[7] = (f16)b.w;
    return v;
}

// ======================= TIER A =======================
#define XK 320                    // x/h panel K stride (halves)
#define WXLS 328                  // LDS W col stride (halves, bank spread)
#define XBYTES   ((size_t)TT * 4096 * XK * 2)        // 57,671,680
#define GXPER    ((size_t)TT * 64 * 512)             // elems per wg
#define GXBYTES  ((size_t)NWG * GXPER * 2)           // 219,152,384
#define HBYTES   ((size_t)2 * 4096 * XK * 2)         // 5,242,880
#define FLBYTES  ((size_t)65536)
#define TIERA_BYTES (FLBYTES + XBYTES + GXBYTES + HBYTES)

__global__ void stage_x_all(const int* __restrict__ cap,
                            const float* __restrict__ embed,
                            f16* __restrict__ xb)
{
    const unsigned NCH = TT * 4096u * 40u;   // f16x8 chunks
    for (unsigned id = blockIdx.x * 256u + threadIdx.x; id < NCH;
         id += gridDim.x * 256u) {
        unsigned t  = id / (4096u * 40u);
        unsigned r2 = id - t * 4096u * 40u;
        unsigned row = r2 / 40u, k8 = r2 - row * 40u;
        int tok = cap[row * TT + t];
        const float* er = embed + (size_t)tok * 300;
        f16* dst = xb + ((size_t)t * 4096 + row) * XK + k8 * 8;
        unsigned k0 = k8 * 8;
        f16x8 v;
        if (k0 < 296) {
            v = pack8(*(const float4*)(er + k0), *(const float4*)(er + k0 + 4));
        } else if (k0 == 296) {
            float4 a = *(const float4*)(er + 296);
            v[0] = (f16)a.x; v[1] = (f16)a.y; v[2] = (f16)a.z; v[3] = (f16)a.w;
            v[4] = v[5] = v[6] = v[7] = (f16)0.f;
        } else {
            #pragma unroll
            for (int i = 0; i < 8; ++i) v[i] = (f16)0.f;
        }
        *(f16x8*)dst = v;
    }
}

__global__ __launch_bounds__(1024, 1)
void gx_pre(const float* __restrict__ Wih,
            const float* __restrict__ bih, const float* __restrict__ bhh,
            const f16* __restrict__ xb, f16* __restrict__ gxb)
{
    __shared__ f16 Wl[64 * WXLS];
    const int tid = threadIdx.x, b = blockIdx.x;
    const int grp = b & 7, nb = b >> 3;
    const int mrow0 = grp * GROWS;
    const int wv = tid >> 6, ln = tid & 63, c = ln & 15, kg = ln >> 4;

    for (int u = tid; u < 64 * 41; u += 1024) {
        int col = u / 41, k8 = u - col * 41;
        int g = col >> 4, cc = col & 15;
        int jh0 = nb * 16 + cc;
        int j = g * 300 + jh0;
        f16x8 v;
        #pragma unroll
        for (int i = 0; i < 8; ++i) {
            int kk = k8 * 8 + i;
            float x = (jh0 < 300 && kk < 300) ? Wih[(size_t)j * 300 + kk] : 0.f;
            v[i] = (f16)x;
        }
        *(f16x8*)&Wl[col * WXLS + k8 * 8] = v;
    }
    __syncthreads();

    const int jh = nb * 16 + c;
    float bias[4];
    #pragma unroll
    for (int g = 0; g < 4; ++g)
        bias[g] = (jh < 300) ? bih[g * 300 + jh] + bhh[g * 300 + jh] : 0.f;
    int bbase[4];
    #pragma unroll
    for (int g = 0; g < 4; ++g) bbase[g] = (g * 16 + c) * WXLS + kg * 8;
    size_t arow[2];
    #pragma unroll
    for (int m = 0; m < 2; ++m)
        arow[m] = (size_t)(mrow0 + wv * 32 + m * 16 + c) * XK + kg * 8;

    f16* gxw = gxb + (size_t)b * GXPER;

    #pragma unroll 1
    for (int t = 0; t < TT; ++t) {
        f32x4 acc[2][4];
        #pragma unroll
        for (int m = 0; m < 2; ++m)
            #pragma unroll
            for (int g = 0; g < 4; ++g) {
                float bv = bias[g];
                f32x4 b4 = {bv, bv, bv, bv};
                acc[m][g] = b4;
            }
        const f16* xt = xb + (size_t)t * 4096 * XK;
        #pragma unroll
        for (int kt = 0; kt < 10; ++kt) {
            f16x8 av[2];
            #pragma unroll
            for (int m = 0; m < 2; ++m)
                av[m] = *(const f16x8*)(xt + arow[m] + kt * 32);
            #pragma unroll
            for (int g = 0; g < 4; ++g) {
                f16x8 bv = *(const f16x8*)&Wl[bbase[g] + kt * 32];
                #pragma unroll
                for (int m = 0; m < 2; ++m)
                    acc[m][g] = __builtin_amdgcn_mfma_f32_16x16x32_f16(av[m], bv, acc[m][g], 0, 0, 0);
            }
        }
        #pragma unroll
        for (int m = 0; m < 2; ++m)
            #pragma unroll
            for (int g = 0; g < 4; ++g) {
                f16x4 o;
                #pragma unroll
                for (int rg = 0; rg < 4; ++rg) o[rg] = (f16)acc[m][g][rg];
                *(f16x4*)(gxw + ((size_t)(t * 64 + g * 16 + c) * 512
                                 + wv * 32 + m * 16 + kg * 4)) = o;
            }
    }
}

#define SROWS 27

__global__ __launch_bounds__(1024, 1)
void lstm_rec(const int* __restrict__ cap_len,
              const float* __restrict__ Whh,
              const float* __restrict__ v_wn, const float* __restrict__ g_wn,
              const float* __restrict__ b_cls,
              const f16* __restrict__ gxb, f16* __restrict__ hbuf,
              unsigned* __restrict__ bar, float* __restrict__ out)
{
    __shared__ f16 Wl[64 * WXLS];
    __shared__ float scaleS[2];
    __shared__ unsigned idsS[NB];

    const int tid = threadIdx.x, b = blockIdx.x;
    const int grp = b & 7, nb = b >> 3;
    const int mrow0 = grp * GROWS;
    const int wv = tid >> 6, ln = tid & 63, c = ln & 15, kg = ln >> 4;

    unsigned* flags = bar + grp * 1024;
    unsigned* ids   = bar + grp * 1024 + 768;

    if (tid == 0)
        (void)__hip_atomic_load(flags, __ATOMIC_ACQUIRE, __HIP_MEMORY_SCOPE_AGENT);
    unsigned xcc;
    asm volatile("s_getreg_b32 %0, hwreg(HW_REG_XCC_ID)" : "=s"(xcc));
    if (tid == 0)
        __hip_atomic_store(ids + nb, xcc + 1u, __ATOMIC_RELAXED,
                           __HIP_MEMORY_SCOPE_AGENT);

    for (int u = tid; u < 64 * 41; u += 1024) {
        int col = u / 41, k8 = u - col * 41;
        int g = col >> 4, cc = col & 15;
        int jh0 = nb * 16 + cc;
        int j = g * 300 + jh0;
        f16x8 v;
        #pragma unroll
        for (int i = 0; i < 8; ++i) {
            int kk = k8 * 8 + i;
            float x = (jh0 < 300 && kk < 300) ? Whh[(size_t)j * 300 + kk] : 0.f;
            v[i] = (f16)x;
        }
        *(f16x8*)&Wl[col * WXLS + k8 * 8] = v;
    }
    if (tid < 2) {
        float s = 0.f;
        for (int k = 0; k < 300; ++k) { float v = v_wn[tid * 300 + k]; s += v * v; }
        scaleS[tid] = g_wn[tid] * rsqrtf(s);
    }
    __syncthreads();

    auto arrive = [&](unsigned ph, bool rel) {
        __syncthreads();
        if (tid == 0) {
            if (rel)
                __hip_atomic_store(flags + nb * 32, ph, __ATOMIC_RELEASE,
                                   __HIP_MEMORY_SCOPE_AGENT);
            else
                __hip_atomic_store(flags + nb * 32, ph, __ATOMIC_RELAXED,
                                   __HIP_MEMORY_SCOPE_AGENT);
        }
    };
    auto wait = [&](unsigned ph, bool fen) {
        if (tid < NB) {
            while (__hip_atomic_load(flags + tid * 32, __ATOMIC_RELAXED,
                                     __HIP_MEMORY_SCOPE_AGENT) < ph)
                __builtin_amdgcn_s_sleep(1);
        }
        if (fen)
            __builtin_amdgcn_fence(__ATOMIC_ACQUIRE, "agent");
        __syncthreads();
    };

    int bbase[4];
    #pragma unroll
    for (int g = 0; g < 4; ++g) bbase[g] = (g * 16 + c) * WXLS + kg * 8;
    size_t aoff[2];
    #pragma unroll
    for (int m = 0; m < 2; ++m)
        aoff[m] = (size_t)(mrow0 + wv * 32 + m * 16 + c) * XK + kg * 8;

    const int jh = nb * 16 + c;
    int lenr[2][4];
    #pragma unroll
    for (int m = 0; m < 2; ++m) {
        int rb = mrow0 + wv * 32 + m * 16 + kg * 4;
        #pragma unroll
        for (int rg = 0; rg < 4; ++rg) lenr[m][rg] = cap_len[rb + rg];
    }

    const f16* gxr = gxb + (size_t)b * GXPER;
    float cst[2][4] = {};
    float hreg[2][4] = {};

    arrive(1, true);
    wait(1, true);

    if (tid < NB)
        idsS[tid] = __hip_atomic_load(ids + tid, __ATOMIC_RELAXED,
                                      __HIP_MEMORY_SCOPE_AGENT);
    __syncthreads();
    bool fastp = true;
    #pragma unroll 1
    for (int i = 1; i < NB; ++i) fastp = fastp && (idsS[i] == idsS[0]);

    #pragma unroll 1
    for (int t = 0; t < STEPS; ++t) {
        // gx prefetch + acc init (own-wg data, no dependency -> before wait)
        f32x4 acc[2][4];
        #pragma unroll
        for (int m = 0; m < 2; ++m)
            #pragma unroll
            for (int g = 0; g < 4; ++g) {
                f16x4 gv = *(const f16x4*)(gxr + ((size_t)(t * 64 + g * 16 + c) * 512
                                                  + wv * 32 + m * 16 + kg * 4));
                #pragma unroll
                for (int rg = 0; rg < 4; ++rg) acc[m][g][rg] = (float)gv[rg];
            }

        if (t > 0) {
            wait((unsigned)(t + 1), true);
            const f16* bufc = hbuf + (size_t)(t & 1) * 4096 * XK;
            #pragma unroll
            for (int kt = 0; kt < 10; ++kt) {
                f16x8 av[2];
                #pragma unroll
                for (int m = 0; m < 2; ++m)
                    av[m] = *(const f16x8*)(bufc + aoff[m] + kt * 32);
                #pragma unroll
                for (int g = 0; g < 4; ++g) {
                    f16x8 bv = *(const f16x8*)&Wl[bbase[g] + kt * 32];
                    #pragma unroll
                    for (int m = 0; m < 2; ++m)
                        acc[m][g] = __builtin_amdgcn_mfma_f32_16x16x32_f16(av[m], bv, acc[m][g], 0, 0, 0);
                }
            }
        }

        f16* bufn = hbuf + (size_t)((t + 1) & 1) * 4096 * XK;
        #pragma unroll
        for (int m = 0; m < 2; ++m) {
            #pragma unroll
            for (int rg = 0; rg < 4; ++rg) {
                bool upd = (t < lenr[m][rg]);
                float iv = sigm(acc[m][0][rg]);
                float fv = sigm(acc[m][1][rg]);
                float gv = tanh_f(acc[m][2][rg]);
                float ov = sigm(acc[m][3][rg]);
                float cn = fv * cst[m][rg] + iv * gv;
                cn = upd ? cn : cst[m][rg];
                cst[m][rg] = cn;
                float hn = ov * tanh_f(cn);
                hreg[m][rg] = upd ? hn : hreg[m][rg];
            }
            if (jh < 300) {
                int rb = mrow0 + wv * 32 + m * 16 + kg * 4;
                #pragma unroll
                for (int rg = 0; rg < 4; ++rg)
                    bufn[(size_t)(rb + rg) * XK + jh] = (f16)hreg[m][rg];
            }
        }
        arrive((unsigned)(t + 2), !fastp);
    }

    wait((unsigned)(STEPS + 1), true);

    // head: this wg's 27 (or 26) rows
    const int srow0 = nb * SROWS;
    const int nr = (GROWS - srow0) < SROWS ? (GROWS - srow0) : SROWS;
    const f16* hb = hbuf + (size_t)(STEPS & 1) * 4096 * XK;
    for (int u = tid; u < nr * 2; u += 1024) {
        int rl = u >> 1, cls = u & 1;
        int grow = mrow0 + srow0 + rl;
        float sc = scaleS[cls];
        const float* vr = v_wn + cls * 300;
        const f16* hr = hb + (size_t)grow * XK;
        float s = 0.f;
        #pragma unroll 4
        for (int k = 0; k < 300; ++k) s += vr[k] * (float)hr[k];
        out[(size_t)grow * 2 + cls] = sc * s + b_cls[cls];
    }
}

// ======================= TIER C (round-9 fallback, verbatim) =======================
#define XSTR 608
#define WLS 616
#define BROWS 4096
#define BUFELT ((size_t)BROWS * XSTR)
#define NTHRC 512

__global__ __launch_bounds__(NTHRC, 2)
void lstm_ws_fb(const int* __restrict__ cap, const int* __restrict__ cap_len,
                const float* __restrict__ embed,
                const float* __restrict__ Wih, const float* __restrict__ Whh,
                const float* __restrict__ bih, const float* __restrict__ bhh,
                const float* __restrict__ v_wn, const float* __restrict__ g_wn,
                const float* __restrict__ b_cls,
                f16* __restrict__ bufs, int depth,
                unsigned* __restrict__ bar, float* __restrict__ out)
{
    __shared__ f16 Wl[64 * WLS];
    __shared__ int capS[SROWS][TT];
    __shared__ float scaleS[2];
    __shared__ unsigned idsS[NB];

    const int tid = threadIdx.x;
    const int b   = blockIdx.x;
    const int grp = b & 7;
    const int nb  = b >> 3;
    const int mrow0 = grp * GROWS;
    const int wv = tid >> 6, ln = tid & 63, c = ln & 15, kg = ln >> 4;
    const bool ahead2 = (depth >= 3);

    unsigned* flags = bar + grp * 1024;
    unsigned* ids   = bar + grp * 1024 + 768;

    if (tid == 0)
        (void)__hip_atomic_load(flags, __ATOMIC_ACQUIRE, __HIP_MEMORY_SCOPE_AGENT);
    unsigned xcc;
    asm volatile("s_getreg_b32 %0, hwreg(HW_REG_XCC_ID)" : "=s"(xcc));
    if (tid == 0)
        __hip_atomic_store(ids + nb, xcc + 1u, __ATOMIC_RELAXED,
                           __HIP_MEMORY_SCOPE_AGENT);

    auto slot = [&](int n) { return bufs + (size_t)(n % depth) * BUFELT; };

    for (int u = tid; u < 64 * 76; u += NTHRC) {
        int col = u / 76, k8 = u - col * 76;
        int g = col >> 4, cc = col & 15;
        int jh0 = nb * 16 + cc;
        int j = g * 300 + jh0;
        f16x8 v;
        #pragma unroll
        for (int i = 0; i < 8; ++i) {
            int kk = k8 * 8 + i;
            float x = 0.f;
            if (jh0 < 300) {
                if (kk < 300)      x = Wih[(size_t)j * 300 + kk];
                else if (kk < 600) x = Whh[(size_t)j * 300 + (kk - 300)];
            }
            v[i] = (f16)x;
        }
        *(f16x8*)&Wl[col * WLS + k8 * 8] = v;
    }

    const int srow0 = nb * SROWS;
    const int nr = (GROWS - srow0) < SROWS ? (GROWS - srow0) : SROWS;
    for (int u = tid; u < SROWS * TT; u += NTHRC) {
        int rl = u / TT, t = u - rl * TT;
        if (rl < nr) capS[rl][t] = cap[(size_t)(mrow0 + srow0 + rl) * TT + t];
    }
    if (tid < 2) {
        float s = 0.f;
        for (int k = 0; k < 300; ++k) { float v = v_wn[tid * 300 + k]; s += v * v; }
        scaleS[tid] = g_wn[tid] * rsqrtf(s);
    }
    __syncthreads();

    auto stage_x = [&](int t, f16* bufn) {
        for (int u = tid; u < nr * 38; u += NTHRC) {
            int rl = u / 38, ch = u - rl * 38;
            int grow = mrow0 + srow0 + rl;
            const float* er = embed + (size_t)capS[rl][t] * 300;
            f16* dst = bufn + (size_t)grow * XSTR;
            int k0 = ch * 8;
            if (ch < 37) {
                float4 a = *(const float4*)(er + k0);
                float4 bb = *(const float4*)(er + k0 + 4);
                *(f16x8*)(dst + k0) = pack8(a, bb);
            } else {
                float4 a = *(const float4*)(er + 296);
                f16* d2 = dst + 296;
                d2[0] = (f16)a.x; d2[1] = (f16)a.y; d2[2] = (f16)a.z; d2[3] = (f16)a.w;
            }
        }
    };

    auto arrive = [&](unsigned ph, bool rel) {
        __syncthreads();
        if (tid == 0) {
            if (rel)
                __hip_atomic_store(flags + nb * 32, ph, __ATOMIC_RELEASE,
                                   __HIP_MEMORY_SCOPE_AGENT);
            else
                __hip_atomic_store(flags + nb * 32, ph, __ATOMIC_RELAXED,
                                   __HIP_MEMORY_SCOPE_AGENT);
        }
    };
    auto wait = [&](unsigned ph, bool fen) {
        if (tid < NB) {
            while (__hip_atomic_load(flags + tid * 32, __ATOMIC_RELAXED,
                                     __HIP_MEMORY_SCOPE_AGENT) < ph)
                __builtin_amdgcn_s_sleep(1);
        }
        if (fen)
            __builtin_amdgcn_fence(__ATOMIC_ACQUIRE, "agent");
        __syncthreads();
    };

    int aoff[4];
    #pragma unroll
    for (int m = 0; m < 4; ++m)
        aoff[m] = (mrow0 + wv * 64 + m * 16 + c) * XSTR + kg * 8;
    int bbase[4];
    #pragma unroll
    for (int g = 0; g < 4; ++g) bbase[g] = (g * 16 + c) * WLS + kg * 8;

    const int jh = nb * 16 + c;
    float bias[4];
    #pragma unroll
    for (int g = 0; g < 4; ++g) {
        float bv = 0.f;
        if (jh < 300) { int j = g * 300 + jh; bv = bih[j] + bhh[j]; }
        bias[g] = bv;
    }
    int lenr[4][4];
    #pragma unroll
    for (int m = 0; m < 4; ++m) {
        int rb = mrow0 + wv * 64 + m * 16 + kg * 4;
        #pragma unroll
        for (int rg = 0; rg < 4; ++rg) lenr[m][rg] = cap_len[rb + rg];
    }

    float cst[4][4] = {};
    float hreg[4][4] = {};
    f32x4 acc[4][4];

    auto xpart = [&](const f16* bufc) {
        #pragma unroll
        for (int kt = 0; kt < 9; ++kt) {
            f16x8 av[4];
            #pragma unroll
            for (int m = 0; m < 4; ++m)
                av[m] = *(const f16x8*)(bufc + aoff[m] + kt * 32);
            #pragma unroll
            for (int g = 0; g < 4; ++g) {
                f16x8 bv = *(const f16x8*)&Wl[bbase[g] + kt * 32];
                #pragma unroll
                for (int m = 0; m < 4; ++m)
                    acc[m][g] = __builtin_amdgcn_mfma_f32_16x16x32_f16(av[m], bv, acc[m][g], 0, 0, 0);
            }
        }
    };
    auto hpart = [&](const f16* bufc) {
        #pragma unroll
        for (int kt = 9; kt < 19; ++kt) {
            f16x8 av[4];
            #pragma unroll
            for (int m = 0; m < 4; ++m)
                av[m] = *(const f16x8*)(bufc + aoff[m] + kt * 32);
            #pragma unroll
            for (int g = 0; g < 4; ++g) {
                f16x8 bv = *(const f16x8*)&Wl[bbase[g] + kt * 32];
                #pragma unroll
                for (int m = 0; m < 4; ++m)
                    acc[m][g] = __builtin_amdgcn_mfma_f32_16x16x32_f16(av[m], bv, acc[m][g], 0, 0, 0);
            }
        }
    };

    stage_x(0, slot(0));
    if (ahead2) stage_x(1, slot(1));
    arrive(1, true);
    wait(1, true);

    if (tid < NB)
        idsS[tid] = __hip_atomic_load(ids + tid, __ATOMIC_RELAXED,
                                      __HIP_MEMORY_SCOPE_AGENT);
    __syncthreads();
    bool fastp = true;
    #pragma unroll 1
    for (int i = 1; i < NB; ++i) fastp = fastp && (idsS[i] == idsS[0]);

    #pragma unroll 1
    for (int t = 0; t < STEPS; ++t) {
        const f16* bufc = slot(t);
        #pragma unroll
        for (int m = 0; m < 4; ++m)
            #pragma unroll
            for (int g = 0; g < 4; ++g) {
                float bv = bias[g];
                f32x4 b4 = {bv, bv, bv, bv};
                acc[m][g] = b4;
            }

        bool reuse = (unsigned)(t + 1) >= (unsigned)depth;
        if (ahead2) {
            xpart(bufc);
            wait((unsigned)(t + 1), reuse);
        } else {
            wait((unsigned)(t + 1), reuse);
            xpart(bufc);
        }
        hpart(bufc);

        f16* bufn = slot(t + 1);
        #pragma unroll
        for (int m = 0; m < 4; ++m) {
            #pragma unroll
            for (int rg = 0; rg < 4; ++rg) {
                bool upd = (t < lenr[m][rg]);
                float iv = sigm(acc[m][0][rg]);
                float fv = sigm(acc[m][1][rg]);
                float gv = tanh_f(acc[m][2][rg]);
                float ov = sigm(acc[m][3][rg]);
                float cn = fv * cst[m][rg] + iv * gv;
                cn = upd ? cn : cst[m][rg];
                cst[m][rg] = cn;
                float hn = ov * tanh_f(cn);
                hreg[m][rg] = upd ? hn : hreg[m][rg];
            }
            if (jh < 300) {
                int rb = mrow0 + wv * 64 + m * 16 + kg * 4;
                #pragma unroll
                for (int rg = 0; rg < 4; ++rg)
                    bufn[(size_t)(rb + rg) * XSTR + 300 + jh] = (f16)hreg[m][rg];
            }
        }

        if (ahead2) { if (t + 2 < STEPS) stage_x(t + 2, slot(t + 2)); }
        else        { if (t + 1 < STEPS) stage_x(t + 1, slot(t + 1)); }
        arrive((unsigned)(t + 2), !fastp);
    }

    wait((unsigned)(STEPS + 1), true);

    const f16* hb = slot(STEPS);
    for (int u = tid; u < nr * 2; u += NTHRC) {
        int rl = u >> 1, cls = u & 1;
        int grow = mrow0 + srow0 + rl;
        float sc = scaleS[cls];
        const float* vr = v_wn + cls * 300;
        const f16* hr = hb + (size_t)grow * XSTR + 300;
        float s = 0.f;
        #pragma unroll 4
        for (int k = 0; k < 300; ++k) s += vr[k] * (float)hr[k];
        out[(size_t)grow * 2 + cls] = sc * s + b_cls[cls];
    }
}

extern "C" void kernel_launch(void* const* d_in, const int* in_sizes, int n_in,
                              void* d_out, int out_size, void* d_ws, size_t ws_size,
                              hipStream_t stream) {
    const int*   cap     = (const int*)  d_in[0];
    const int*   cap_len = (const int*)  d_in[1];
    const float* embed   = (const float*)d_in[2];
    const float* W_ih    = (const float*)d_in[3];
    const float* W_hh    = (const float*)d_in[4];
    const float* b_ih    = (const float*)d_in[5];
    const float* b_hh    = (const float*)d_in[6];
    const float* v_wn    = (const float*)d_in[7];
    const float* g_wn    = (const float*)d_in[8];
    const float* b_cls   = (const float*)d_in[9];
    float* out = (float*)d_out;

    if (ws_size >= TIERA_BYTES) {
        unsigned* bar = (unsigned*)d_ws;
        f16* xb   = (f16*)((char*)d_ws + FLBYTES);
        f16* gxb  = (f16*)((char*)d_ws + FLBYTES + XBYTES);
        f16* hbuf = (f16*)((char*)d_ws + FLBYTES + XBYTES + GXBYTES);

        hipMemsetAsync(bar, 0, FLBYTES, stream);      // flags + ids
        hipMemsetAsync(hbuf, 0, HBYTES, stream);      // h slots (h0=0 + K-pad)

        stage_x_all<<<2048, 256, 0, stream>>>(cap, embed, xb);
        gx_pre<<<NWG, 1024, 0, stream>>>(W_ih, b_ih, b_hh, xb, gxb);
        lstm_rec<<<NWG, 1024, 0, stream>>>(cap_len, W_hh, v_wn, g_wn, b_cls,
                                           gxb, hbuf, bar, out);
    } else {
        unsigned* bar = (unsigned*)d_ws;
        f16* bufs = (f16*)((char*)d_ws + 65536);
        size_t slot_bytes = BUFELT * sizeof(f16);
        int depth = (int)((ws_size > 65536 ? ws_size - 65536 : 0) / slot_bytes);
        if (depth > STEPS + 1) depth = STEPS + 1;
        if (depth < 2) depth = 2;

        hipMemsetAsync(bar, 0, 65536, stream);
        hipMemsetAsync(bufs, 0, slot_bytes, stream);

        lstm_ws_fb<<<NWG, NTHRC, 0, stream>>>(cap, cap_len, embed, W_ih, W_hh,
                                              b_ih, b_hh, v_wn, g_wn, b_cls,
                                              bufs, depth, bar, out);
    }
}

// Round 11
// 418.785 us; speedup vs baseline: 1.8698x; 1.0302x over previous
//
#include <hip/hip_runtime.h>
#include <hip/hip_fp16.h>

// Weight-stationary LSTM classifier; exchange buffer PRE-SWIZZLED to MFMA
// fragment layout (kills the 64-line gather that dominated rounds 3-10).
// B=4096, T=22, E=H=300. 8 groups (512 rows) x 19 wgs (16 jh x 4 gates);
// grid 152, grp=b&7. 1024 thr (16 waves, 4/SIMD). W block (64 cols x 640 k
// fp16, LDS stride 680) stationary.
// Swizzled panel: K=640 (x:0..319 | h:320..639), addr(row,k) =
//   ((row>>4)*20 + k/32)*1024B + (row&15)*64B + ((k>>3)&3)*16B + (k&7)*2B
// -> a wave's A-fragment load (16 rows x 32 k) is ONE contiguous 1KB block.
// Per step: xpart (kt 0..9) BEFORE wait (x staged 2 ahead, depth>=3);
// hpart (kt 10..19) after; gates i/f/g/o same-lane; h stored swizzled
// (pad cols written 0; unwritten pad x W=0 in MFMA). Round-9 sync verbatim:
// RMW-free store-release flags, same-XCD fastpath vote (XCC_ID), slot
// rotation w/ acquire-fence on reuse, entry acquire for graph replay.
// d_ws: [0,64KB) flags+ids, then depth x 5.24MB swizzled slots.

#define TT 22
#define STEPS 22
#define NB 19
#define NGRP 8
#define GROWS 512
#define NWG (NB * NGRP)          // 152
#define NTHR 1024
#define KTOT 20                  // kt blocks (640 halves)
#define WLS 680                  // LDS W col stride (halves); 340 words %32=20
#define BUFELT ((size_t)256 * KTOT * 512)   // 4096/16 tiles * 20kt * 512 halves
#define SROWS 27                 // staging rows per wg (ceil 512/19)

typedef _Float16 f16;
typedef _Float16 f16x8 __attribute__((ext_vector_type(8)));
typedef float    f32x4 __attribute__((ext_vector_type(4)));

__device__ __forceinline__ float sigm(float x) { return 1.0f / (1.0f + __expf(-x)); }
__device__ __forceinline__ float tanh_f(float x) {
    float ax = fabsf(x);
    float e = __expf(-2.0f * ax);
    return copysignf((1.0f - e) / (1.0f + e), x);
}
__device__ __forceinline__ f16x8 pack8(float4 a, float4 b) {
    f16x8 v;
    v[0] = (f16)a.x; v[1] = (f16)a.y; v[2] = (f16)a.z; v[3] = (f16)a.w;
    v[4] = (f16)b.x; v[5] = (f16)b.y; v[6] = (f16)b.z; v[7] = (f16)b.w;
    return v;
}

__global__ __launch_bounds__(NTHR, 4)
void lstm_ws(const int* __restrict__ cap, const int* __restrict__ cap_len,
             const float* __restrict__ embed,
             const float* __restrict__ Wih, const float* __restrict__ Whh,
             const float* __restrict__ bih, const float* __restrict__ bhh,
             const float* __restrict__ v_wn, const float* __restrict__ g_wn,
             const float* __restrict__ b_cls,
             f16* __restrict__ bufs, int depth,
             unsigned* __restrict__ bar, float* __restrict__ out)
{
    __shared__ f16 Wl[64 * WLS];     // 87KB stationary weights (K=640 w/ pads)
    __shared__ int capS[SROWS][TT];
    __shared__ float scaleS[2];
    __shared__ unsigned idsS[NB];

    const int tid = threadIdx.x;
    const int b   = blockIdx.x;
    const int grp = b & 7;           // group; fastpath verifies physical XCD
    const int nb  = b >> 3;          // 0..18 jh-tile
    const int mrow0 = grp * GROWS;
    const int wv = tid >> 6, ln = tid & 63, c = ln & 15, kg = ln >> 4;

    unsigned* flags = bar + grp * 1024;        // wg flag at + nb*32
    unsigned* ids   = bar + grp * 1024 + 768;

    if (tid == 0)
        (void)__hip_atomic_load(flags, __ATOMIC_ACQUIRE, __HIP_MEMORY_SCOPE_AGENT);
    unsigned xcc;
    asm volatile("s_getreg_b32 %0, hwreg(HW_REG_XCC_ID)" : "=s"(xcc));
    if (tid == 0)
        __hip_atomic_store(ids + nb, xcc + 1u, __ATOMIC_RELAXED,
                           __HIP_MEMORY_SCOPE_AGENT);

    auto slot = [&](int n) { return bufs + (size_t)(n % depth) * BUFELT; };

    // ---- W -> LDS: col=g*16+cc; k: [0,300)=Wih | [320,620)=Whh | else 0 ----
    for (int u = tid; u < 64 * 80; u += NTHR) {
        int col = u / 80, k8 = u - col * 80;
        int g = col >> 4, cc = col & 15;
        int jh0 = nb * 16 + cc;
        int j = g * 300 + jh0;
        f16x8 v;
        #pragma unroll
        for (int i = 0; i < 8; ++i) {
            int kk = k8 * 8 + i;
            float x = 0.f;
            if (jh0 < 300) {
                if (kk < 300)                   x = Wih[(size_t)j * 300 + kk];
                else if (kk >= 320 && kk < 620) x = Whh[(size_t)j * 300 + (kk - 320)];
            }
            v[i] = (f16)x;
        }
        *(f16x8*)&Wl[col * WLS + k8 * 8] = v;
    }

    const int srow0 = nb * SROWS;
    const int nr = (GROWS - srow0) < SROWS ? (GROWS - srow0) : SROWS;  // 27/26
    for (int u = tid; u < SROWS * TT; u += NTHR) {
        int rl = u / TT, t = u - rl * TT;
        if (rl < nr) capS[rl][t] = cap[(size_t)(mrow0 + srow0 + rl) * TT + t];
    }
    if (tid < 2) {
        float s = 0.f;
        for (int k = 0; k < 300; ++k) { float v = v_wn[tid * 300 + k]; s += v * v; }
        scaleS[tid] = g_wn[tid] * rsqrtf(s);
    }
    __syncthreads();

    // ---- x staging into swizzled layout (k8 chunks 0..39; 37..39 padded) ----
    auto stage_x = [&](int t, f16* bufn) {
        for (int u = tid; u < nr * 40; u += NTHR) {
            int rl = u / 40, k8 = u - rl * 40;
            int grow = mrow0 + srow0 + rl;
            const float* er = embed + (size_t)capS[rl][t] * 300;
            int k0 = k8 * 8;
            f16x8 v;
            if (k0 < 296) {
                v = pack8(*(const float4*)(er + k0), *(const float4*)(er + k0 + 4));
            } else if (k0 == 296) {
                float4 a = *(const float4*)(er + 296);
                v[0] = (f16)a.x; v[1] = (f16)a.y; v[2] = (f16)a.z; v[3] = (f16)a.w;
                v[4] = v[5] = v[6] = v[7] = (f16)0.f;
            } else {
                #pragma unroll
                for (int i = 0; i < 8; ++i) v[i] = (f16)0.f;
            }
            size_t off = ((size_t)((grow >> 4) * KTOT + (k8 >> 2))) * 512
                         + (grow & 15) * 32 + (k8 & 3) * 8;
            *(f16x8*)(bufn + off) = v;
        }
    };

    auto arrive = [&](unsigned ph, bool rel) {
        __syncthreads();
        if (tid == 0) {
            if (rel)
                __hip_atomic_store(flags + nb * 32, ph, __ATOMIC_RELEASE,
                                   __HIP_MEMORY_SCOPE_AGENT);
            else
                __hip_atomic_store(flags + nb * 32, ph, __ATOMIC_RELAXED,
                                   __HIP_MEMORY_SCOPE_AGENT);
        }
    };
    auto wait = [&](unsigned ph, bool fen) {
        if (tid < NB) {
            while (__hip_atomic_load(flags + tid * 32, __ATOMIC_RELAXED,
                                     __HIP_MEMORY_SCOPE_AGENT) < ph)
                __builtin_amdgcn_s_sleep(1);
        }
        if (fen)
            __builtin_amdgcn_fence(__ATOMIC_ACQUIRE, "agent");
        __syncthreads();
    };

    // per-lane constants: wave owns rows [mrow0 + wv*32, +32) (2 m-tiles)
    size_t aoff[2];
    #pragma unroll
    for (int m = 0; m < 2; ++m)
        aoff[m] = (size_t)(((mrow0 >> 4) + wv * 2 + m) * KTOT) * 512
                  + c * 32 + kg * 8;
    int bbase[4];
    #pragma unroll
    for (int g = 0; g < 4; ++g) bbase[g] = (g * 16 + c) * WLS + kg * 8;

    const int jh = nb * 16 + c;
    float bias[4];
    #pragma unroll
    for (int g = 0; g < 4; ++g) {
        float bv = 0.f;
        if (jh < 300) { int j = g * 300 + jh; bv = bih[j] + bhh[j]; }
        bias[g] = bv;
    }
    int lenr[2][4];
    #pragma unroll
    for (int m = 0; m < 2; ++m) {
        int rb = mrow0 + wv * 32 + m * 16 + kg * 4;
        #pragma unroll
        for (int rg = 0; rg < 4; ++rg) lenr[m][rg] = cap_len[rb + rg];
    }
    // h-store swizzle constants (col k = 320 + jh)
    const int hkt  = (320 + jh) >> 5;
    const int hkgd = ((320 + jh) >> 3) & 3;
    const int hel  = jh & 7;

    float cst[2][4] = {};
    float hreg[2][4] = {};
    f32x4 acc[2][4];

    auto xpart = [&](const f16* bufc) {   // kt 0..9 (x region)
        #pragma unroll
        for (int kt = 0; kt < 10; ++kt) {
            f16x8 av[2];
            #pragma unroll
            for (int m = 0; m < 2; ++m)
                av[m] = *(const f16x8*)(bufc + aoff[m] + kt * 512);
            #pragma unroll
            for (int g = 0; g < 4; ++g) {
                f16x8 bv = *(const f16x8*)&Wl[bbase[g] + kt * 32];
                #pragma unroll
                for (int m = 0; m < 2; ++m)
                    acc[m][g] = __builtin_amdgcn_mfma_f32_16x16x32_f16(av[m], bv, acc[m][g], 0, 0, 0);
            }
        }
    };
    auto hpart = [&](const f16* bufc) {   // kt 10..19 (h region; pads x W=0)
        #pragma unroll
        for (int kt = 10; kt < KTOT; ++kt) {
            f16x8 av[2];
            #pragma unroll
            for (int m = 0; m < 2; ++m)
                av[m] = *(const f16x8*)(bufc + aoff[m] + kt * 512);
            #pragma unroll
            for (int g = 0; g < 4; ++g) {
                f16x8 bv = *(const f16x8*)&Wl[bbase[g] + kt * 32];
                #pragma unroll
                for (int m = 0; m < 2; ++m)
                    acc[m][g] = __builtin_amdgcn_mfma_f32_16x16x32_f16(av[m], bv, acc[m][g], 0, 0, 0);
            }
        }
    };

    const bool ahead2 = (depth >= 3);
    stage_x(0, slot(0));                  // slot0 fully memset: h_0 = 0 + pads
    if (ahead2) stage_x(1, slot(1));
    arrive(1, true);
    wait(1, true);

    if (tid < NB)
        idsS[tid] = __hip_atomic_load(ids + tid, __ATOMIC_RELAXED,
                                      __HIP_MEMORY_SCOPE_AGENT);
    __syncthreads();
    bool fastp = true;
    #pragma unroll 1
    for (int i = 1; i < NB; ++i) fastp = fastp && (idsS[i] == idsS[0]);

    #pragma unroll 1
    for (int t = 0; t < STEPS; ++t) {
        const f16* bufc = slot(t);
        #pragma unroll
        for (int m = 0; m < 2; ++m)
            #pragma unroll
            for (int g = 0; g < 4; ++g) {
                float bv = bias[g];
                f32x4 b4 = {bv, bv, bv, bv};
                acc[m][g] = b4;
            }

        bool reuse = (unsigned)(t + 1) >= (unsigned)depth;
        if (ahead2) {
            xpart(bufc);                   // x(t) synced >= 1 step ago
            wait((unsigned)(t + 1), reuse);
        } else {
            wait((unsigned)(t + 1), reuse);
            xpart(bufc);
        }
        hpart(bufc);

        // gates (i/f/g/o same-lane acc regs) + swizzled h store (pads -> 0)
        f16* bufn = slot(t + 1);
        #pragma unroll
        for (int m = 0; m < 2; ++m) {
            int rtile = (mrow0 >> 4) + wv * 2 + m;
            size_t hb = ((size_t)(rtile * KTOT + hkt)) * 512 + hkgd * 8 + hel;
            #pragma unroll
            for (int rg = 0; rg < 4; ++rg) {
                bool upd = (t < lenr[m][rg]);
                float iv = sigm(acc[m][0][rg]);
                float fv = sigm(acc[m][1][rg]);
                float gv = tanh_f(acc[m][2][rg]);
                float ov = sigm(acc[m][3][rg]);
                float cn = fv * cst[m][rg] + iv * gv;
                cn = upd ? cn : cst[m][rg];
                cst[m][rg] = cn;
                float hn = ov * tanh_f(cn);
                hreg[m][rg] = upd ? hn : hreg[m][rg];
                f16 hv = (jh < 300) ? (f16)hreg[m][rg] : (f16)0.f;
                bufn[hb + (size_t)(kg * 4 + rg) * 32] = hv;
            }
        }

        if (ahead2) { if (t + 2 < STEPS) stage_x(t + 2, slot(t + 2)); }
        else        { if (t + 1 < STEPS) stage_x(t + 1, slot(t + 1)); }
        arrive((unsigned)(t + 2), !fastp);
    }

    wait((unsigned)(STEPS + 1), true);

    // ---- head: this wg's staged rows, swizzled h reads ----
    const f16* hb = slot(STEPS);
    for (int u = tid; u < nr * 2; u += NTHR) {
        int rl = u >> 1, cls = u & 1;
        int grow = mrow0 + srow0 + rl;
        float sc = scaleS[cls];
        const float* vr = v_wn + cls * 300;
        size_t rbase = ((size_t)((grow >> 4) * KTOT)) * 512 + (grow & 15) * 32;
        float s = 0.f;
        #pragma unroll 4
        for (int k = 0; k < 300; ++k) {
            int k2 = 320 + k;
            size_t off = rbase + (size_t)(k2 >> 5) * 512 + ((k2 >> 3) & 3) * 8 + (k2 & 7);
            s += vr[k] * (float)hb[off];
        }
        out[(size_t)grow * 2 + cls] = sc * s + b_cls[cls];
    }
}

extern "C" void kernel_launch(void* const* d_in, const int* in_sizes, int n_in,
                              void* d_out, int out_size, void* d_ws, size_t ws_size,
                              hipStream_t stream) {
    const int*   cap     = (const int*)  d_in[0];
    const int*   cap_len = (const int*)  d_in[1];
    const float* embed   = (const float*)d_in[2];
    const float* W_ih    = (const float*)d_in[3];
    const float* W_hh    = (const float*)d_in[4];
    const float* b_ih    = (const float*)d_in[5];
    const float* b_hh    = (const float*)d_in[6];
    const float* v_wn    = (const float*)d_in[7];
    const float* g_wn    = (const float*)d_in[8];
    const float* b_cls   = (const float*)d_in[9];
    float* out = (float*)d_out;

    unsigned* bar = (unsigned*)d_ws;
    f16* bufs = (f16*)((char*)d_ws + 65536);
    size_t slot_bytes = BUFELT * sizeof(f16);          // 5,242,880
    int depth = (int)((ws_size > 65536 ? ws_size - 65536 : 0) / slot_bytes);
    if (depth > STEPS + 1) depth = STEPS + 1;          // 23 = fully virgin
    if (depth < 2) depth = 2;                          // proven footprint

    hipMemsetAsync(bar, 0, 65536, stream);             // flags + ids
    hipMemsetAsync(bufs, 0, slot_bytes, stream);       // slot 0 (h_0=0 + pads)

    lstm_ws<<<NWG, NTHR, 0, stream>>>(cap, cap_len, embed, W_ih, W_hh, b_ih, b_hh,
                                      v_wn, g_wn, b_cls, bufs, depth, bar, out);
}

// Round 12
// 413.288 us; speedup vs baseline: 1.8946x; 1.0133x over previous
//
#include <hip/hip_runtime.h>
#include <hip/hip_fp16.h>

// Weight-stationary LSTM classifier; exchange buffer in MFMA-fragment layout
// (round 11) + W in LDS stored FRAGMENT-BLOCKED (round 12 fix: the old
// (col*WLS) layout had word-stride ≡ 20 mod 32 -> 8-way bank conflict on
// every B ds_read_b128; 1280 of them per CU per step was the ~17us step).
// Fragment (g,kt) = contiguous 1KB block, lane ln reads [ln*16, ln*16+16) ->
// canonical conflict-free b128 pattern.
// B=4096, T=22, E=H=300. 8 groups (512 rows) x 19 wgs (16 jh x 4 gates);
// grid 152, grp=b&7. 1024 thr (16 waves, 4/SIMD).
// Swizzled exchange panel: K=640 (x:0..319 | h:320..639), addr(row,k) =
//   ((row>>4)*20 + k/32)*1024B + (row&15)*64B + ((k>>3)&3)*16B + (k&7)*2B.
// Per step: xpart (kt 0..9) BEFORE wait (x staged 2 ahead, depth>=3);
// hpart (kt 10..19) after; gates i/f/g/o same-lane; h stored swizzled.
// Round-9 sync verbatim: RMW-free store-release flags, same-XCD fastpath
// vote (XCC_ID), slot rotation w/ acquire-fence on reuse, entry acquire.
// d_ws: [0,64KB) flags+ids, then depth x 5.24MB swizzled slots.

#define TT 22
#define STEPS 22
#define NB 19
#define NGRP 8
#define GROWS 512
#define NWG (NB * NGRP)          // 152
#define NTHR 1024
#define KTOT 20                  // kt blocks (640 halves)
#define BUFELT ((size_t)256 * KTOT * 512)   // 4096/16 tiles * 20kt * 512 halves
#define SROWS 27                 // staging rows per wg (ceil 512/19)

typedef _Float16 f16;
typedef _Float16 f16x8 __attribute__((ext_vector_type(8)));
typedef float    f32x4 __attribute__((ext_vector_type(4)));

__device__ __forceinline__ float sigm(float x) { return 1.0f / (1.0f + __expf(-x)); }
__device__ __forceinline__ float tanh_f(float x) {
    float ax = fabsf(x);
    float e = __expf(-2.0f * ax);
    return copysignf((1.0f - e) / (1.0f + e), x);
}
__device__ __forceinline__ f16x8 pack8(float4 a, float4 b) {
    f16x8 v;
    v[0] = (f16)a.x; v[1] = (f16)a.y; v[2] = (f16)a.z; v[3] = (f16)a.w;
    v[4] = (f16)b.x; v[5] = (f16)b.y; v[6] = (f16)b.z; v[7] = (f16)b.w;
    return v;
}

__global__ __launch_bounds__(NTHR, 4)
void lstm_ws(const int* __restrict__ cap, const int* __restrict__ cap_len,
             const float* __restrict__ embed,
             const float* __restrict__ Wih, const float* __restrict__ Whh,
             const float* __restrict__ bih, const float* __restrict__ bhh,
             const float* __restrict__ v_wn, const float* __restrict__ g_wn,
             const float* __restrict__ b_cls,
             f16* __restrict__ bufs, int depth,
             unsigned* __restrict__ bar, float* __restrict__ out)
{
    __shared__ f16 Wl[80 * 512];     // 80 KB: fragment-blocked W (4g x 20kt)
    __shared__ int capS[SROWS][TT];
    __shared__ float scaleS[2];
    __shared__ unsigned idsS[NB];

    const int tid = threadIdx.x;
    const int b   = blockIdx.x;
    const int grp = b & 7;           // group; fastpath verifies physical XCD
    const int nb  = b >> 3;          // 0..18 jh-tile
    const int mrow0 = grp * GROWS;
    const int wv = tid >> 6, ln = tid & 63, c = ln & 15, kg = ln >> 4;

    unsigned* flags = bar + grp * 1024;        // wg flag at + nb*32
    unsigned* ids   = bar + grp * 1024 + 768;

    if (tid == 0)
        (void)__hip_atomic_load(flags, __ATOMIC_ACQUIRE, __HIP_MEMORY_SCOPE_AGENT);
    unsigned xcc;
    asm volatile("s_getreg_b32 %0, hwreg(HW_REG_XCC_ID)" : "=s"(xcc));
    if (tid == 0)
        __hip_atomic_store(ids + nb, xcc + 1u, __ATOMIC_RELAXED,
                           __HIP_MEMORY_SCOPE_AGENT);

    auto slot = [&](int n) { return bufs + (size_t)(n % depth) * BUFELT; };

    // ---- W -> LDS, fragment-blocked: frag f = g*20+kt is 1KB contiguous.
    // lane l of frag: col = g*16 + (l&15), k = kt*32 + (l>>4)*8 + e.
    // k: [0,300)=Wih | [320,620)=Whh | else 0 (pads multiply as zeros).
    for (int u = tid; u < 80 * 64; u += NTHR) {
        int f = u >> 6, l = u & 63;
        int g = f / KTOT, kt = f - g * KTOT;
        int cc = l & 15, kgg = l >> 4;
        int jh0 = nb * 16 + cc;
        int j = g * 300 + jh0;
        int kb = kt * 32 + kgg * 8;
        f16x8 v;
        #pragma unroll
        for (int i = 0; i < 8; ++i) {
            int kk = kb + i;
            float x = 0.f;
            if (jh0 < 300) {
                if (kk < 300)                   x = Wih[(size_t)j * 300 + kk];
                else if (kk >= 320 && kk < 620) x = Whh[(size_t)j * 300 + (kk - 320)];
            }
            v[i] = (f16)x;
        }
        *(f16x8*)&Wl[(size_t)f * 512 + l * 8] = v;
    }

    const int srow0 = nb * SROWS;
    const int nr = (GROWS - srow0) < SROWS ? (GROWS - srow0) : SROWS;  // 27/26
    for (int u = tid; u < SROWS * TT; u += NTHR) {
        int rl = u / TT, t = u - rl * TT;
        if (rl < nr) capS[rl][t] = cap[(size_t)(mrow0 + srow0 + rl) * TT + t];
    }
    if (tid < 2) {
        float s = 0.f;
        for (int k = 0; k < 300; ++k) { float v = v_wn[tid * 300 + k]; s += v * v; }
        scaleS[tid] = g_wn[tid] * rsqrtf(s);
    }
    __syncthreads();

    // ---- x staging into swizzled layout (k8 chunks 0..39; 37..39 padded) ----
    auto stage_x = [&](int t, f16* bufn) {
        for (int u = tid; u < nr * 40; u += NTHR) {
            int rl = u / 40, k8 = u - rl * 40;
            int grow = mrow0 + srow0 + rl;
            const float* er = embed + (size_t)capS[rl][t] * 300;
            int k0 = k8 * 8;
            f16x8 v;
            if (k0 < 296) {
                v = pack8(*(const float4*)(er + k0), *(const float4*)(er + k0 + 4));
            } else if (k0 == 296) {
                float4 a = *(const float4*)(er + 296);
                v[0] = (f16)a.x; v[1] = (f16)a.y; v[2] = (f16)a.z; v[3] = (f16)a.w;
                v[4] = v[5] = v[6] = v[7] = (f16)0.f;
            } else {
                #pragma unroll
                for (int i = 0; i < 8; ++i) v[i] = (f16)0.f;
            }
            size_t off = ((size_t)((grow >> 4) * KTOT + (k8 >> 2))) * 512
                         + (grow & 15) * 32 + (k8 & 3) * 8;
            *(f16x8*)(bufn + off) = v;
        }
    };

    auto arrive = [&](unsigned ph, bool rel) {
        __syncthreads();
        if (tid == 0) {
            if (rel)
                __hip_atomic_store(flags + nb * 32, ph, __ATOMIC_RELEASE,
                                   __HIP_MEMORY_SCOPE_AGENT);
            else
                __hip_atomic_store(flags + nb * 32, ph, __ATOMIC_RELAXED,
                                   __HIP_MEMORY_SCOPE_AGENT);
        }
    };
    auto wait = [&](unsigned ph, bool fen) {
        if (tid < NB) {
            while (__hip_atomic_load(flags + tid * 32, __ATOMIC_RELAXED,
                                     __HIP_MEMORY_SCOPE_AGENT) < ph)
                __builtin_amdgcn_s_sleep(1);
        }
        if (fen)
            __builtin_amdgcn_fence(__ATOMIC_ACQUIRE, "agent");
        __syncthreads();
    };

    // per-lane constants: wave owns rows [mrow0 + wv*32, +32) (2 m-tiles)
    size_t aoff[2];
    #pragma unroll
    for (int m = 0; m < 2; ++m)
        aoff[m] = (size_t)(((mrow0 >> 4) + wv * 2 + m) * KTOT) * 512
                  + c * 32 + kg * 8;
    int wbase[4];
    #pragma unroll
    for (int g = 0; g < 4; ++g) wbase[g] = g * KTOT * 512 + ln * 8;

    const int jh = nb * 16 + c;
    float bias[4];
    #pragma unroll
    for (int g = 0; g < 4; ++g) {
        float bv = 0.f;
        if (jh < 300) { int j = g * 300 + jh; bv = bih[j] + bhh[j]; }
        bias[g] = bv;
    }
    int lenr[2][4];
    #pragma unroll
    for (int m = 0; m < 2; ++m) {
        int rb = mrow0 + wv * 32 + m * 16 + kg * 4;
        #pragma unroll
        for (int rg = 0; rg < 4; ++rg) lenr[m][rg] = cap_len[rb + rg];
    }
    // h-store swizzle constants (col k = 320 + jh)
    const int hkt  = (320 + jh) >> 5;
    const int hkgd = ((320 + jh) >> 3) & 3;
    const int hel  = jh & 7;

    float cst[2][4] = {};
    float hreg[2][4] = {};
    f32x4 acc[2][4];

    auto xpart = [&](const f16* bufc) {   // kt 0..9 (x region)
        #pragma unroll
        for (int kt = 0; kt < 10; ++kt) {
            f16x8 av[2];
            #pragma unroll
            for (int m = 0; m < 2; ++m)
                av[m] = *(const f16x8*)(bufc + aoff[m] + kt * 512);
            #pragma unroll
            for (int g = 0; g < 4; ++g) {
                f16x8 bv = *(const f16x8*)&Wl[wbase[g] + kt * 512];
                #pragma unroll
                for (int m = 0; m < 2; ++m)
                    acc[m][g] = __builtin_amdgcn_mfma_f32_16x16x32_f16(av[m], bv, acc[m][g], 0, 0, 0);
            }
        }
    };
    auto hpart = [&](const f16* bufc) {   // kt 10..19 (h region; pads x W=0)
        #pragma unroll
        for (int kt = 10; kt < KTOT; ++kt) {
            f16x8 av[2];
            #pragma unroll
            for (int m = 0; m < 2; ++m)
                av[m] = *(const f16x8*)(bufc + aoff[m] + kt * 512);
            #pragma unroll
            for (int g = 0; g < 4; ++g) {
                f16x8 bv = *(const f16x8*)&Wl[wbase[g] + kt * 512];
                #pragma unroll
                for (int m = 0; m < 2; ++m)
                    acc[m][g] = __builtin_amdgcn_mfma_f32_16x16x32_f16(av[m], bv, acc[m][g], 0, 0, 0);
            }
        }
    };

    const bool ahead2 = (depth >= 3);
    stage_x(0, slot(0));                  // slot0 fully memset: h_0 = 0 + pads
    if (ahead2) stage_x(1, slot(1));
    arrive(1, true);
    wait(1, true);

    if (tid < NB)
        idsS[tid] = __hip_atomic_load(ids + tid, __ATOMIC_RELAXED,
                                      __HIP_MEMORY_SCOPE_AGENT);
    __syncthreads();
    bool fastp = true;
    #pragma unroll 1
    for (int i = 1; i < NB; ++i) fastp = fastp && (idsS[i] == idsS[0]);

    #pragma unroll 1
    for (int t = 0; t < STEPS; ++t) {
        const f16* bufc = slot(t);
        #pragma unroll
        for (int m = 0; m < 2; ++m)
            #pragma unroll
            for (int g = 0; g < 4; ++g) {
                float bv = bias[g];
                f32x4 b4 = {bv, bv, bv, bv};
                acc[m][g] = b4;
            }

        bool reuse = (unsigned)(t + 1) >= (unsigned)depth;
        if (ahead2) {
            xpart(bufc);                   // x(t) synced >= 1 step ago
            wait((unsigned)(t + 1), reuse);
        } else {
            wait((unsigned)(t + 1), reuse);
            xpart(bufc);
        }
        hpart(bufc);

        // gates (i/f/g/o same-lane acc regs) + swizzled h store (pads -> 0)
        f16* bufn = slot(t + 1);
        #pragma unroll
        for (int m = 0; m < 2; ++m) {
            int rtile = (mrow0 >> 4) + wv * 2 + m;
            size_t hb = ((size_t)(rtile * KTOT + hkt)) * 512 + hkgd * 8 + hel;
            #pragma unroll
            for (int rg = 0; rg < 4; ++rg) {
                bool upd = (t < lenr[m][rg]);
                float iv = sigm(acc[m][0][rg]);
                float fv = sigm(acc[m][1][rg]);
                float gv = tanh_f(acc[m][2][rg]);
                float ov = sigm(acc[m][3][rg]);
                float cn = fv * cst[m][rg] + iv * gv;
                cn = upd ? cn : cst[m][rg];
                cst[m][rg] = cn;
                float hn = ov * tanh_f(cn);
                hreg[m][rg] = upd ? hn : hreg[m][rg];
                f16 hv = (jh < 300) ? (f16)hreg[m][rg] : (f16)0.f;
                bufn[hb + (size_t)(kg * 4 + rg) * 32] = hv;
            }
        }

        if (ahead2) { if (t + 2 < STEPS) stage_x(t + 2, slot(t + 2)); }
        else        { if (t + 1 < STEPS) stage_x(t + 1, slot(t + 1)); }
        arrive((unsigned)(t + 2), !fastp);
    }

    wait((unsigned)(STEPS + 1), true);

    // ---- head: this wg's staged rows, swizzled h reads ----
    const f16* hb = slot(STEPS);
    for (int u = tid; u < nr * 2; u += NTHR) {
        int rl = u >> 1, cls = u & 1;
        int grow = mrow0 + srow0 + rl;
        float sc = scaleS[cls];
        const float* vr = v_wn + cls * 300;
        size_t rbase = ((size_t)((grow >> 4) * KTOT)) * 512 + (grow & 15) * 32;
        float s = 0.f;
        #pragma unroll 4
        for (int k = 0; k < 300; ++k) {
            int k2 = 320 + k;
            size_t off = rbase + (size_t)(k2 >> 5) * 512 + ((k2 >> 3) & 3) * 8 + (k2 & 7);
            s += vr[k] * (float)hb[off];
        }
        out[(size_t)grow * 2 + cls] = sc * s + b_cls[cls];
    }
}

extern "C" void kernel_launch(void* const* d_in, const int* in_sizes, int n_in,
                              void* d_out, int out_size, void* d_ws, size_t ws_size,
                              hipStream_t stream) {
    const int*   cap     = (const int*)  d_in[0];
    const int*   cap_len = (const int*)  d_in[1];
    const float* embed   = (const float*)d_in[2];
    const float* W_ih    = (const float*)d_in[3];
    const float* W_hh    = (const float*)d_in[4];
    const float* b_ih    = (const float*)d_in[5];
    const float* b_hh    = (const float*)d_in[6];
    const float* v_wn    = (const float*)d_in[7];
    const float* g_wn    = (const float*)d_in[8];
    const float* b_cls   = (const float*)d_in[9];
    float* out = (float*)d_out;

    unsigned* bar = (unsigned*)d_ws;
    f16* bufs = (f16*)((char*)d_ws + 65536);
    size_t slot_bytes = BUFELT * sizeof(f16);          // 5,242,880
    int depth = (int)((ws_size > 65536 ? ws_size - 65536 : 0) / slot_bytes);
    if (depth > STEPS + 1) depth = STEPS + 1;          // 23 = fully virgin
    if (depth < 2) depth = 2;                          // proven footprint

    hipMemsetAsync(bar, 0, 65536, stream);             // flags + ids
    hipMemsetAsync(bufs, 0, slot_bytes, stream);       // slot 0 (h_0=0 + pads)

    lstm_ws<<<NWG, NTHR, 0, stream>>>(cap, cap_len, embed, W_ih, W_hh, b_ih, b_hh,
                                      v_wn, g_wn, b_cls, bufs, depth, bar, out);
}